// Round 3
// baseline (523.406 us; speedup 1.0000x reference)
//
#include <hip/hip_runtime.h>
#include <math.h>

#define TSEQ 2048
#define DM   768
#define NH   12
#define HD   64
#define NBH  24

// round(linspace(0, 2047, 32)) — verified against fp32 evaluation (no .5 ties)
__constant__ int c_idxp[32] = {0,66,132,198,264,330,396,462,528,594,660,726,
  792,858,924,990,1057,1123,1189,1255,1321,1387,1453,1519,1585,1651,1717,1783,
  1849,1915,1981,2047};

__device__ __forceinline__ float wsum(float v) {
#pragma unroll
  for (int m = 1; m < 64; m <<= 1) v += __shfl_xor(v, m, 64);
  return v;
}
__device__ __forceinline__ float wmaxr(float v) {
#pragma unroll
  for (int m = 1; m < 64; m <<= 1) v = fmaxf(v, __shfl_xor(v, m, 64));
  return v;
}

// ---------------- GEMM: dst = (X @ W^T + bias) * scale ----------------
// BM=BN=128, BK=16, 256 threads, 8x8 per thread (2x2 quadrants of 4x4).
// k-accumulation order per output element is IDENTICAL to the sequential
// fp32 reference order used before (k0 outer, kk inner) -> bit-stable
// selections.
// MODE 0: row-major [M,DM] store.  MODE 1: qkv layout store (b*NH+h, t, dd).
template <int MODE>
__device__ __forceinline__ void gemm_body(const float* __restrict__ X,
                                          const float* __restrict__ W,
                                          const float* __restrict__ bias,
                                          float* __restrict__ dst, float scale,
                                          int mblk, int nblk,
                                          float (*As)[132], float (*Bs)[132]) {
  const int tid = threadIdx.x;   // 256
  const int tr = tid >> 4;       // 0..15 row group
  const int tc = tid & 15;       // 0..15 col group
  const int lr = tid >> 1;       // staging row 0..127
  const int lc = (tid & 1) * 8;  // staging k offset {0,8}
  const float* Xp = X + (size_t)(mblk + lr) * DM + lc;
  const float* Wp = W + (size_t)(nblk + lr) * DM + lc;

  float acc[2][2][4][4] = {};
  float4 a0n = *(const float4*)(Xp + 0);
  float4 a1n = *(const float4*)(Xp + 4);
  float4 b0n = *(const float4*)(Wp + 0);
  float4 b1n = *(const float4*)(Wp + 4);

  for (int k0 = 0; k0 < DM; k0 += 16) {
    __syncthreads();  // previous tile's compute done before overwrite
    As[lc + 0][lr] = a0n.x; As[lc + 1][lr] = a0n.y;
    As[lc + 2][lr] = a0n.z; As[lc + 3][lr] = a0n.w;
    As[lc + 4][lr] = a1n.x; As[lc + 5][lr] = a1n.y;
    As[lc + 6][lr] = a1n.z; As[lc + 7][lr] = a1n.w;
    Bs[lc + 0][lr] = b0n.x; Bs[lc + 1][lr] = b0n.y;
    Bs[lc + 2][lr] = b0n.z; Bs[lc + 3][lr] = b0n.w;
    Bs[lc + 4][lr] = b1n.x; Bs[lc + 5][lr] = b1n.y;
    Bs[lc + 6][lr] = b1n.z; Bs[lc + 7][lr] = b1n.w;
    __syncthreads();
    if (k0 + 16 < DM) {  // prefetch next tile; overlaps the 16-kk compute
      a0n = *(const float4*)(Xp + k0 + 16);
      a1n = *(const float4*)(Xp + k0 + 20);
      b0n = *(const float4*)(Wp + k0 + 16);
      b1n = *(const float4*)(Wp + k0 + 20);
    }
#pragma unroll
    for (int kk = 0; kk < 16; ++kk) {
      float4 A0 = *(const float4*)&As[kk][tr * 4];        // 16-lane broadcast
      float4 A1 = *(const float4*)&As[kk][tr * 4 + 64];
      float4 B0 = *(const float4*)&Bs[kk][tc * 4];        // 2-way banks: free
      float4 B1 = *(const float4*)&Bs[kk][tc * 4 + 64];
      float ar[2][4] = {{A0.x, A0.y, A0.z, A0.w}, {A1.x, A1.y, A1.z, A1.w}};
      float br[2][4] = {{B0.x, B0.y, B0.z, B0.w}, {B1.x, B1.y, B1.z, B1.w}};
#pragma unroll
      for (int ih = 0; ih < 2; ++ih)
#pragma unroll
        for (int jh = 0; jh < 2; ++jh)
#pragma unroll
          for (int i = 0; i < 4; ++i)
#pragma unroll
            for (int j = 0; j < 4; ++j)
              acc[ih][jh][i][j] = fmaf(ar[ih][i], br[jh][j], acc[ih][jh][i][j]);
    }
  }

#pragma unroll
  for (int jh = 0; jh < 2; ++jh) {
    const int col = nblk + jh * 64 + tc * 4;
    const float b0 = bias[col + 0], b1 = bias[col + 1];
    const float b2 = bias[col + 2], b3 = bias[col + 3];
#pragma unroll
    for (int ih = 0; ih < 2; ++ih) {
#pragma unroll
      for (int i = 0; i < 4; ++i) {
        int row = mblk + ih * 64 + tr * 4 + i;
        float4 o;
        o.x = (acc[ih][jh][i][0] + b0) * scale;
        o.y = (acc[ih][jh][i][1] + b1) * scale;
        o.z = (acc[ih][jh][i][2] + b2) * scale;
        o.w = (acc[ih][jh][i][3] + b3) * scale;
        if (MODE == 0) {
          *(float4*)&dst[(size_t)row * DM + col] = o;
        } else {
          int b_ = row >> 11, t = row & (TSEQ - 1);
          int h = col >> 6, dd = col & 63;
          *(float4*)&dst[(((size_t)(b_ * NH + h)) * TSEQ + t) * HD + dd] = o;
        }
      }
    }
  }
}

__global__ __launch_bounds__(256) void qkv_kernel(
    const float* __restrict__ X,
    const float* __restrict__ Wq, const float* __restrict__ bq, float* __restrict__ qd,
    const float* __restrict__ Wk, const float* __restrict__ bk, float* __restrict__ kd,
    const float* __restrict__ Wv, const float* __restrict__ bv, float* __restrict__ vd) {
  __shared__ float As[16][132];
  __shared__ float Bs[16][132];
  int z = blockIdx.z;
  const float* W = (z == 0) ? Wq : (z == 1) ? Wk : Wv;
  const float* bias = (z == 0) ? bq : (z == 1) ? bk : bv;
  float* dst = (z == 0) ? qd : (z == 1) ? kd : vd;
  float scale = (z == 0) ? 0.125f : 1.0f;
  gemm_body<1>(X, W, bias, dst, scale, blockIdx.y * 128, blockIdx.x * 128, As, Bs);
}

__global__ __launch_bounds__(256) void oproj_kernel(
    const float* __restrict__ X, const float* __restrict__ W,
    const float* __restrict__ bias, float* __restrict__ dst) {
  __shared__ float As[16][132];
  __shared__ float Bs[16][132];
  gemm_body<0>(X, W, bias, dst, 1.0f, blockIdx.y * 128, blockIdx.x * 128, As, Bs);
}

// ---------------- window selection: one wave per (bh, t) ----------------
// lane = f*4 + g : fragment f in [0,16), dim-group g in [0,4) (16 dims each).
__global__ __launch_bounds__(256) void window_kernel(
    const float* __restrict__ q, const float* __restrict__ k,
    int* __restrict__ sel) {
  int wid = blockIdx.x * 4 + (threadIdx.x >> 6);
  int lane = threadIdx.x & 63;
  int f = lane >> 2, g = lane & 3;
  int bh = wid >> 11, t = wid & (TSEQ - 1);
  int start = t - 8;
  if (start < 0) start = 0;
  if (start > TSEQ - 16) start = TSEQ - 16;

  const float* qp = q + ((size_t)bh * TSEQ + t) * HD + g * 16;
  const float* kp = k + ((size_t)bh * TSEQ + start + f) * HD + g * 16;
  float qv[16], kn[16];
#pragma unroll
  for (int j = 0; j < 4; ++j) {
    float4 qq = *(const float4*)(qp + j * 4);
    float4 kk = *(const float4*)(kp + j * 4);
    qv[j * 4 + 0] = qq.x; qv[j * 4 + 1] = qq.y; qv[j * 4 + 2] = qq.z; qv[j * 4 + 3] = qq.w;
    kn[j * 4 + 0] = kk.x; kn[j * 4 + 1] = kk.y; kn[j * 4 + 2] = kk.z; kn[j * 4 + 3] = kk.w;
  }
  float sp = 0.f, np = 0.f;
#pragma unroll
  for (int i = 0; i < 16; ++i) { sp = fmaf(qv[i], kn[i], sp); np = fmaf(kn[i], kn[i], np); }
  sp += __shfl_xor(sp, 1, 64); sp += __shfl_xor(sp, 2, 64);
  np += __shfl_xor(np, 1, 64); np += __shfl_xor(np, 2, 64);
  float nrm = fmaxf(sqrtf(np), 1e-6f);
#pragma unroll
  for (int i = 0; i < 16; ++i) kn[i] = kn[i] / nrm;  // match ref: kw / max(norm,eps)

  int dist = start + f - t; if (dist < 0) dist = -dist;
  float tmp = sp + 0.2f * expf(-(float)dist * 0.125f);

  int* selp = sel + ((size_t)bh * TSEQ + t) * 6;
#pragma unroll
  for (int r = 0; r < 6; ++r) {
    // wave argmax over f with first-max (smallest f) tie-break, as jnp.argmax
    float best = tmp; int bj = f;
#pragma unroll
    for (int m = 1; m < 64; m <<= 1) {
      float ov = __shfl_xor(best, m, 64);
      int oi = __shfl_xor(bj, m, 64);
      if (ov > best || (ov == best && oi < bj)) { best = ov; bj = oi; }
    }
    if (lane == 0) selp[r] = start + bj;
    if (r < 5) {
      float cp = 0.f;
      int src = (bj << 2) | g;
#pragma unroll
      for (int i = 0; i < 16; ++i) {
        float knj = __shfl(kn[i], src, 64);
        cp = fmaf(kn[i], knj, cp);
      }
      cp += __shfl_xor(cp, 1, 64); cp += __shfl_xor(cp, 2, 64);
      tmp -= 0.2f * fmaxf(cp, 0.f);  // penalty applied before masking (ref order)
    }
    if (f == bj) tmp = -1e9f;
  }
}

// ---------------- prototype queries Qp[a][p][:] ----------------
__global__ __launch_bounds__(256) void qp_kernel(const float* __restrict__ q,
                                                 float* __restrict__ Qp) {
  int wid = blockIdx.x * 4 + (threadIdx.x >> 6);  // 0..383
  int lane = threadIdx.x & 63;
  int a = wid >> 5, p = wid & 31;
  int t = c_idxp[p];
  float v = 0.5f * (q[((size_t)(2 * a) * TSEQ + t) * HD + lane] +
                    q[((size_t)(2 * a + 1) * TSEQ + t) * HD + lane]);
  float n2 = wsum(v * v);
  float nrm = fmaxf(sqrtf(n2), 1e-6f);
  Qp[((size_t)a * 32 + p) * HD + lane] = v / nrm;
}

// ---------------- S[a][t][p] and u[a][t] ----------------
__global__ __launch_bounds__(256) void proto_score_kernel(
    const float* __restrict__ k, const float* __restrict__ Qp,
    float* __restrict__ S, float* __restrict__ u) {
  int a = blockIdx.y;
  __shared__ float Qs[2048];
  for (int i = threadIdx.x; i < 2048; i += 256) Qs[i] = Qp[(size_t)a * 2048 + i];
  __syncthreads();
  int w = threadIdx.x >> 6, lane = threadIdx.x & 63;
  int t = blockIdx.x * 4 + w;
  float km = 0.5f * (k[((size_t)(2 * a) * TSEQ + t) * HD + lane] +
                     k[((size_t)(2 * a + 1) * TSEQ + t) * HD + lane]);
  float n2 = wsum(km * km);
  float nrm = fmaxf(sqrtf(n2), 1e-6f);
  float kb = km / nrm;
  float sval = 0.f;
#pragma unroll
  for (int p = 0; p < 32; ++p) {
    float dg = wsum(kb * Qs[p * 64 + lane]);
    dg = fmaxf(dg, 0.f);               // relu
    sval = (lane == p) ? dg : sval;    // lane p keeps S_p
  }
  if (lane < 32) S[((size_t)a * TSEQ + t) * 32 + lane] = sval;
  float x = (lane < 32) ? sval : 0.f;
  float mean = wsum(x) / 32.0f;
  float mx = wmaxr((lane < 32) ? sval : -1e30f);
  float cur = (lane < 32) ? sval : -1e30f;
  float topsum = 0.f;
#pragma unroll
  for (int r = 0; r < 6; ++r) {        // top-6 values (remove one instance each)
    float m = wmaxr(cur);
    topsum += m;
    unsigned long long ball = __ballot(cur == m);
    int first = __ffsll(ball) - 1;
    if (lane == first) cur = -1e30f;
  }
  float dev = (lane < 32) ? (sval - mean) : 0.f;
  float sd = sqrtf(wsum(dev * dev) / 31.0f);  // ddof=1
  float uval = ((1.0f * mean + 0.6f * mx) + 0.4f * (topsum / 6.0f)) + 0.2f * sd;
  if (lane == 0) u[(size_t)a * TSEQ + t] = uval;
}

// ---------------- per-head top-12 + greedy facility location ----------------
__global__ void head_select_kernel(const float* __restrict__ u,
                                   const float* __restrict__ S,
                                   int* __restrict__ glob) {
  int a = blockIdx.x;
  int lane = threadIdx.x;  // 64 threads
  float uv[32];
#pragma unroll
  for (int c = 0; c < 32; ++c) uv[c] = u[(size_t)a * TSEQ + c * 64 + lane];
  unsigned removed = 0;
  int tidx = 0;
#pragma unroll
  for (int r = 0; r < 12; ++r) {
    float best = -1e30f; int bidx = 1 << 30;
#pragma unroll
    for (int c = 0; c < 32; ++c) {
      if (!((removed >> c) & 1u)) {
        float vv = uv[c]; int gi = c * 64 + lane;
        if (vv > best || (vv == best && gi < bidx)) { best = vv; bidx = gi; }
      }
    }
#pragma unroll
    for (int mS = 1; mS < 64; mS <<= 1) {
      float ov = __shfl_xor(best, mS, 64);
      int oi = __shfl_xor(bidx, mS, 64);
      if (ov > best || (ov == best && oi < bidx)) { best = ov; bidx = oi; }
    }
    if (lane == (bidx & 63)) removed |= 1u << (bidx >> 6);
    if (lane == r) tidx = bidx;   // lane r remembers top_idx[r]
  }
  float srow[12];
#pragma unroll
  for (int r = 0; r < 12; ++r) {
    int tr = __shfl(tidx, r, 64);
    srow[r] = (lane < 32) ? S[((size_t)a * TSEQ + tr) * 32 + lane] : 0.f;
  }
  float m = 0.f;
  unsigned blocked = 0;
#pragma unroll
  for (int g = 0; g < 4; ++g) {
    float gains[12];
#pragma unroll
    for (int r = 0; r < 12; ++r) {
      float gr = (lane < 32) ? fmaxf(srow[r] - m, 0.f) : 0.f;
      gains[r] = wsum(gr);
    }
    float best = -1e30f; int bj = 0;
#pragma unroll
    for (int r = 0; r < 12; ++r) {
      float vv = ((blocked >> r) & 1u) ? -1e9f : gains[r];
      if (vv > best) { best = vv; bj = r; }  // first-max
    }
    blocked |= 1u << bj;
#pragma unroll
    for (int r = 0; r < 12; ++r) m = (r == bj) ? fmaxf(m, srow[r]) : m;
    int gidx = __shfl(tidx, bj, 64);
    if (lane == 0) glob[a * 4 + g] = gidx;
  }
}

// ---------------- final 10-candidate attention ----------------
__global__ __launch_bounds__(256) void attend_kernel(
    const float* __restrict__ q, const float* __restrict__ k,
    const float* __restrict__ v, const int* __restrict__ sel,
    const int* __restrict__ glob, float* __restrict__ preout) {
  int wid = blockIdx.x * 4 + (threadIdx.x >> 6);
  int lane = threadIdx.x & 63;
  int bh = wid >> 11, t = wid & (TSEQ - 1);
  int h = bh % NH, b = bh / NH;
  float qv = q[((size_t)bh * TSEQ + t) * HD + lane];
  int cand[10];
  const int* selp = sel + ((size_t)bh * TSEQ + t) * 6;
#pragma unroll
  for (int c = 0; c < 6; ++c) cand[c] = selp[c];
#pragma unroll
  for (int c = 0; c < 4; ++c) cand[6 + c] = glob[h * 4 + c];
  float sc[10];
#pragma unroll
  for (int c = 0; c < 10; ++c) {
    float kv = k[((size_t)bh * TSEQ + cand[c]) * HD + lane];
    sc[c] = wsum(qv * kv);
  }
  float mx = sc[0];
#pragma unroll
  for (int c = 1; c < 10; ++c) mx = fmaxf(mx, sc[c]);
  float e[10], den = 0.f;
#pragma unroll
  for (int c = 0; c < 10; ++c) { e[c] = expf(sc[c] - mx); den += e[c]; }
  float o = 0.f;
#pragma unroll
  for (int c = 0; c < 10; ++c) {
    float w = e[c] / den;
    o += w * v[((size_t)bh * TSEQ + cand[c]) * HD + lane];
  }
  preout[((size_t)b * TSEQ + t) * DM + h * HD + lane] = o;
}

extern "C" void kernel_launch(void* const* d_in, const int* in_sizes, int n_in,
                              void* d_out, int out_size, void* d_ws, size_t ws_size,
                              hipStream_t stream) {
  const float* x  = (const float*)d_in[0];
  const float* Wq = (const float*)d_in[1];
  const float* bq = (const float*)d_in[2];
  const float* Wk = (const float*)d_in[3];
  const float* bk = (const float*)d_in[4];
  const float* Wv = (const float*)d_in[5];
  const float* bv = (const float*)d_in[6];
  const float* Wo = (const float*)d_in[7];
  const float* bo = (const float*)d_in[8];
  float* out = (float*)d_out;

  float* ws = (float*)d_ws;
  const size_t QKV = (size_t)NBH * TSEQ * HD;  // 3145728
  float* qb = ws;
  float* kb = qb + QKV;
  float* vb = kb + QKV;
  float* preout = vb + QKV;
  float* Qp = preout + (size_t)2 * TSEQ * DM;  // 3145728
  float* S  = Qp + (size_t)NH * 32 * HD;       // 24576
  float* u  = S + (size_t)NH * TSEQ * 32;      // 786432
  int* sel  = (int*)(u + (size_t)NH * TSEQ);   // 24576
  int* glob = sel + (size_t)NBH * TSEQ * 6;    // 294912 ints

  qkv_kernel<<<dim3(6, 32, 3), 256, 0, stream>>>(x, Wq, bq, qb, Wk, bk, kb, Wv, bv, vb);
  window_kernel<<<12288, 256, 0, stream>>>(qb, kb, sel);
  qp_kernel<<<96, 256, 0, stream>>>(qb, Qp);
  proto_score_kernel<<<dim3(512, NH), 256, 0, stream>>>(kb, Qp, S, u);
  head_select_kernel<<<NH, 64, 0, stream>>>(u, S, glob);
  attend_kernel<<<12288, 256, 0, stream>>>(qb, kb, vb, sel, glob, preout);
  oproj_kernel<<<dim3(6, 32, 1), 256, 0, stream>>>(preout, Wo, bo, out);
}

// Round 5
// 376.869 us; speedup vs baseline: 1.3888x; 1.3888x over previous
//
#include <hip/hip_runtime.h>
#include <math.h>

#define TSEQ 2048
#define DM   768
#define NH   12
#define HD   64
#define NBH  24

typedef __attribute__((ext_vector_type(8))) short short8;
typedef __attribute__((ext_vector_type(4))) float f32x4;

#define MFMA_BF16(a, b, c) __builtin_amdgcn_mfma_f32_16x16x32_bf16(a, b, c, 0, 0, 0)

// round(linspace(0, 2047, 32)) — verified against fp32 evaluation (no .5 ties)
__constant__ int c_idxp[32] = {0,66,132,198,264,330,396,462,528,594,660,726,
  792,858,924,990,1057,1123,1189,1255,1321,1387,1453,1519,1585,1651,1717,1783,
  1849,1915,1981,2047};

__device__ __forceinline__ float wsum(float v) {
#pragma unroll
  for (int m = 1; m < 64; m <<= 1) v += __shfl_xor(v, m, 64);
  return v;
}
__device__ __forceinline__ float wmaxr(float v) {
#pragma unroll
  for (int m = 1; m < 64; m <<= 1) v = fmaxf(v, __shfl_xor(v, m, 64));
  return v;
}

__device__ __forceinline__ ushort bf16rne(float x) {
  unsigned u = __float_as_uint(x);
  return (ushort)((u + 0x7fffu + ((u >> 16) & 1u)) >> 16);
}

// split 8 fp32 -> bf16 h/m/l (RNE each stage; subtractions exact)
template <bool NEED_L>
__device__ __forceinline__ void split_store(const float4& v0, const float4& v1,
                                            ushort* ph, ushort* pm, ushort* pl) {
  float xs[8] = {v0.x, v0.y, v0.z, v0.w, v1.x, v1.y, v1.z, v1.w};
  short8 h, m, l;
#pragma unroll
  for (int j = 0; j < 8; ++j) {
    float x = xs[j];
    ushort hb = bf16rne(x);
    h[j] = (short)hb;
    float d = x - __uint_as_float((unsigned)hb << 16);
    ushort mb = bf16rne(d);
    m[j] = (short)mb;
    if (NEED_L) {
      float d2 = d - __uint_as_float((unsigned)mb << 16);
      l[j] = (short)bf16rne(d2);
    }
  }
  *(short8*)ph = h;
  *(short8*)pm = m;
  if (NEED_L) *(short8*)pl = l;
}

// ---------------- split-bf16 MFMA GEMM: dst = (A @ B^T + bias) * scale ------
// A [M,768] fp32, B [N,768] fp32; split to bf16 h/m/l during LDS staging.
// NPROD=6: hh+mh+hm+mm+lh+hl (error ~2^-25, selection-safe).
// NPROD=3: hh+mh+hm (error ~2^-18, value-path only).
// 128x128 tile, BK=32, 256 thr = 4 waves (2x2), 4x4 16x16x32 frags/wave.
// MODE 0: row-major [M,DM] store.  MODE 1: qkv layout store (b*NH+h,t,dd).
template <int MODE, int NPROD>
__device__ __forceinline__ void gemm_mfma_body(
    const float* __restrict__ A, const float* __restrict__ B,
    const float* __restrict__ bias, float* __restrict__ dst, float scale,
    int mblk, int nblk, ushort* lds) {
  const int tid = threadIdx.x;
  const int lane = tid & 63;
  const int w = tid >> 6;
  const int wr = w >> 1, wc = w & 1;
  const int lrow = lane & 15, kq = lane >> 4;
  constexpr int BUF = 128 * 40;
  ushort* Ahs = lds;
  ushort* Ams = lds + BUF;
  ushort* Als = (NPROD == 6) ? lds + 2 * BUF : nullptr;
  ushort* Bhs = lds + ((NPROD == 6) ? 3 : 2) * BUF;
  ushort* Bms = Bhs + BUF;
  ushort* Bls = (NPROD == 6) ? Bhs + 2 * BUF : nullptr;

  f32x4 acc[4][4];
#pragma unroll
  for (int i = 0; i < 4; ++i)
#pragma unroll
    for (int j = 0; j < 4; ++j) {
      f32x4 z = {0.f, 0.f, 0.f, 0.f};
      acc[i][j] = z;
    }

  // prefetch registers: [it] covering 512 8-elem segments / 256 threads
  float4 pa0[2], pa1[2], pb0[2], pb1[2];
#pragma unroll
  for (int it = 0; it < 2; ++it) {
    int seg = it * 256 + tid, srow = seg >> 2, skq = (seg & 3) * 8;
    pa0[it] = *(const float4*)(A + (size_t)(mblk + srow) * DM + skq);
    pa1[it] = *(const float4*)(A + (size_t)(mblk + srow) * DM + skq + 4);
    pb0[it] = *(const float4*)(B + (size_t)(nblk + srow) * DM + skq);
    pb1[it] = *(const float4*)(B + (size_t)(nblk + srow) * DM + skq + 4);
  }

  for (int k0 = 0; k0 < DM; k0 += 32) {
    __syncthreads();
#pragma unroll
    for (int it = 0; it < 2; ++it) {
      int seg = it * 256 + tid, srow = seg >> 2, skq = (seg & 3) * 8;
      int o = srow * 40 + skq;
      split_store<NPROD == 6>(pa0[it], pa1[it], Ahs + o, Ams + o,
                              (NPROD == 6) ? Als + o : nullptr);
      split_store<NPROD == 6>(pb0[it], pb1[it], Bhs + o, Bms + o,
                              (NPROD == 6) ? Bls + o : nullptr);
    }
    __syncthreads();
    if (k0 + 32 < DM) {  // prefetch next K-tile; overlaps MFMA
#pragma unroll
      for (int it = 0; it < 2; ++it) {
        int seg = it * 256 + tid, srow = seg >> 2, skq = (seg & 3) * 8;
        pa0[it] = *(const float4*)(A + (size_t)(mblk + srow) * DM + k0 + 32 + skq);
        pa1[it] = *(const float4*)(A + (size_t)(mblk + srow) * DM + k0 + 36 + skq);
        pb0[it] = *(const float4*)(B + (size_t)(nblk + srow) * DM + k0 + 32 + skq);
        pb1[it] = *(const float4*)(B + (size_t)(nblk + srow) * DM + k0 + 36 + skq);
      }
    }
    short8 afh[4], afm[4], afl[4];
#pragma unroll
    for (int fi = 0; fi < 4; ++fi) {
      int o = (wr * 64 + fi * 16 + lrow) * 40 + kq * 8;
      afh[fi] = *(const short8*)&Ahs[o];
      afm[fi] = *(const short8*)&Ams[o];
      if (NPROD == 6) afl[fi] = *(const short8*)&Als[o];
    }
#pragma unroll
    for (int fj = 0; fj < 4; ++fj) {
      int o = (wc * 64 + fj * 16 + lrow) * 40 + kq * 8;
      short8 bfh = *(const short8*)&Bhs[o];
      short8 bfm = *(const short8*)&Bms[o];
      short8 bfl;
      if (NPROD == 6) bfl = *(const short8*)&Bls[o];
#pragma unroll
      for (int fi = 0; fi < 4; ++fi) {
        acc[fi][fj] = MFMA_BF16(afh[fi], bfh, acc[fi][fj]);
        acc[fi][fj] = MFMA_BF16(afm[fi], bfh, acc[fi][fj]);
        acc[fi][fj] = MFMA_BF16(afh[fi], bfm, acc[fi][fj]);
        if (NPROD == 6) {
          acc[fi][fj] = MFMA_BF16(afm[fi], bfm, acc[fi][fj]);
          acc[fi][fj] = MFMA_BF16(afl[fi], bfh, acc[fi][fj]);
          acc[fi][fj] = MFMA_BF16(afh[fi], bfl, acc[fi][fj]);
        }
      }
    }
  }

#pragma unroll
  for (int fj = 0; fj < 4; ++fj) {
    int col = nblk + wc * 64 + fj * 16 + lrow;
    float bv = bias[col];
#pragma unroll
    for (int fi = 0; fi < 4; ++fi) {
#pragma unroll
      for (int reg = 0; reg < 4; ++reg) {
        int row = mblk + wr * 64 + fi * 16 + kq * 4 + reg;
        float o = (acc[fi][fj][reg] + bv) * scale;
        if (MODE == 0) {
          dst[(size_t)row * DM + col] = o;
        } else {
          int b_ = row >> 11, t = row & (TSEQ - 1);
          int h = col >> 6, dd = col & 63;
          dst[(((size_t)(b_ * NH + h)) * TSEQ + t) * HD + dd] = o;
        }
      }
    }
  }
}

__global__ __launch_bounds__(256) void qk_kernel(
    const float* __restrict__ X,
    const float* __restrict__ Wq, const float* __restrict__ bq, float* __restrict__ qd,
    const float* __restrict__ Wk, const float* __restrict__ bk, float* __restrict__ kd) {
  __shared__ ushort lds[6 * 128 * 40];
  int z = blockIdx.z;
  gemm_mfma_body<1, 6>(X, z ? Wk : Wq, z ? bk : bq, z ? kd : qd,
                       z ? 1.0f : 0.125f, blockIdx.y * 128, blockIdx.x * 128, lds);
}

__global__ __launch_bounds__(256) void v_kernel(
    const float* __restrict__ X, const float* __restrict__ Wv,
    const float* __restrict__ bv, float* __restrict__ vd) {
  __shared__ ushort lds[4 * 128 * 40];
  gemm_mfma_body<1, 3>(X, Wv, bv, vd, 1.0f, blockIdx.y * 128, blockIdx.x * 128, lds);
}

__global__ __launch_bounds__(256) void oproj_kernel(
    const float* __restrict__ X, const float* __restrict__ W,
    const float* __restrict__ bias, float* __restrict__ dst) {
  __shared__ ushort lds[4 * 128 * 40];
  gemm_mfma_body<0, 3>(X, W, bias, dst, 1.0f, blockIdx.y * 128, blockIdx.x * 128, lds);
}

// ---------------- window selection: one wave per (bh, t) ----------------
// lane = f*4 + g : fragment f in [0,16), dim-group g in [0,4) (16 dims each).
__global__ __launch_bounds__(256) void window_kernel(
    const float* __restrict__ q, const float* __restrict__ k,
    int* __restrict__ sel) {
  int wid = blockIdx.x * 4 + (threadIdx.x >> 6);
  int lane = threadIdx.x & 63;
  int f = lane >> 2, g = lane & 3;
  int bh = wid >> 11, t = wid & (TSEQ - 1);
  int start = t - 8;
  if (start < 0) start = 0;
  if (start > TSEQ - 16) start = TSEQ - 16;

  const float* qp = q + ((size_t)bh * TSEQ + t) * HD + g * 16;
  const float* kp = k + ((size_t)bh * TSEQ + start + f) * HD + g * 16;
  float qv[16], kn[16];
#pragma unroll
  for (int j = 0; j < 4; ++j) {
    float4 qq = *(const float4*)(qp + j * 4);
    float4 kk = *(const float4*)(kp + j * 4);
    qv[j * 4 + 0] = qq.x; qv[j * 4 + 1] = qq.y; qv[j * 4 + 2] = qq.z; qv[j * 4 + 3] = qq.w;
    kn[j * 4 + 0] = kk.x; kn[j * 4 + 1] = kk.y; kn[j * 4 + 2] = kk.z; kn[j * 4 + 3] = kk.w;
  }
  float sp = 0.f, np = 0.f;
#pragma unroll
  for (int i = 0; i < 16; ++i) { sp = fmaf(qv[i], kn[i], sp); np = fmaf(kn[i], kn[i], np); }
  sp += __shfl_xor(sp, 1, 64); sp += __shfl_xor(sp, 2, 64);
  np += __shfl_xor(np, 1, 64); np += __shfl_xor(np, 2, 64);
  float nrm = fmaxf(sqrtf(np), 1e-6f);
#pragma unroll
  for (int i = 0; i < 16; ++i) kn[i] = kn[i] / nrm;  // match ref: kw / max(norm,eps)

  int dist = start + f - t; if (dist < 0) dist = -dist;
  float tmp = sp + 0.2f * expf(-(float)dist * 0.125f);

  int* selp = sel + ((size_t)bh * TSEQ + t) * 6;
#pragma unroll
  for (int r = 0; r < 6; ++r) {
    // wave argmax over f with first-max (smallest f) tie-break, as jnp.argmax
    float best = tmp; int bj = f;
#pragma unroll
    for (int m = 1; m < 64; m <<= 1) {
      float ov = __shfl_xor(best, m, 64);
      int oi = __shfl_xor(bj, m, 64);
      if (ov > best || (ov == best && oi < bj)) { best = ov; bj = oi; }
    }
    if (lane == 0) selp[r] = start + bj;
    if (r < 5) {
      float cp = 0.f;
      int src = (bj << 2) | g;
#pragma unroll
      for (int i = 0; i < 16; ++i) {
        float knj = __shfl(kn[i], src, 64);
        cp = fmaf(kn[i], knj, cp);
      }
      cp += __shfl_xor(cp, 1, 64); cp += __shfl_xor(cp, 2, 64);
      tmp -= 0.2f * fmaxf(cp, 0.f);  // penalty applied before masking (ref order)
    }
    if (f == bj) tmp = -1e9f;
  }
}

// ---------------- prototype queries Qp[a][p][:] ----------------
__global__ __launch_bounds__(256) void qp_kernel(const float* __restrict__ q,
                                                 float* __restrict__ Qp) {
  int wid = blockIdx.x * 4 + (threadIdx.x >> 6);  // 0..383
  int lane = threadIdx.x & 63;
  int a = wid >> 5, p = wid & 31;
  int t = c_idxp[p];
  float v = 0.5f * (q[((size_t)(2 * a) * TSEQ + t) * HD + lane] +
                    q[((size_t)(2 * a + 1) * TSEQ + t) * HD + lane]);
  float n2 = wsum(v * v);
  float nrm = fmaxf(sqrtf(n2), 1e-6f);
  Qp[((size_t)a * 32 + p) * HD + lane] = v / nrm;
}

// ---------------- S[a][t][p] and u[a][t] ----------------
__global__ __launch_bounds__(256) void proto_score_kernel(
    const float* __restrict__ k, const float* __restrict__ Qp,
    float* __restrict__ S, float* __restrict__ u) {
  int a = blockIdx.y;
  __shared__ float Qs[2048];
  for (int i = threadIdx.x; i < 2048; i += 256) Qs[i] = Qp[(size_t)a * 2048 + i];
  __syncthreads();
  int w = threadIdx.x >> 6, lane = threadIdx.x & 63;
  int t = blockIdx.x * 4 + w;
  float km = 0.5f * (k[((size_t)(2 * a) * TSEQ + t) * HD + lane] +
                     k[((size_t)(2 * a + 1) * TSEQ + t) * HD + lane]);
  float n2 = wsum(km * km);
  float nrm = fmaxf(sqrtf(n2), 1e-6f);
  float kb = km / nrm;
  float sval = 0.f;
#pragma unroll
  for (int p = 0; p < 32; ++p) {
    float dg = wsum(kb * Qs[p * 64 + lane]);
    dg = fmaxf(dg, 0.f);               // relu
    sval = (lane == p) ? dg : sval;    // lane p keeps S_p
  }
  if (lane < 32) S[((size_t)a * TSEQ + t) * 32 + lane] = sval;
  float x = (lane < 32) ? sval : 0.f;
  float mean = wsum(x) / 32.0f;
  float mx = wmaxr((lane < 32) ? sval : -1e30f);
  float cur = (lane < 32) ? sval : -1e30f;
  float topsum = 0.f;
#pragma unroll
  for (int r = 0; r < 6; ++r) {        // top-6 values (remove one instance each)
    float m = wmaxr(cur);
    topsum += m;
    unsigned long long ball = __ballot(cur == m);
    int first = __ffsll(ball) - 1;
    if (lane == first) cur = -1e30f;
  }
  float dev = (lane < 32) ? (sval - mean) : 0.f;
  float sd = sqrtf(wsum(dev * dev) / 31.0f);  // ddof=1
  float uval = ((1.0f * mean + 0.6f * mx) + 0.4f * (topsum / 6.0f)) + 0.2f * sd;
  if (lane == 0) u[(size_t)a * TSEQ + t] = uval;
}

// ---------------- per-head top-12 + greedy facility location ----------------
__global__ void head_select_kernel(const float* __restrict__ u,
                                   const float* __restrict__ S,
                                   int* __restrict__ glob) {
  int a = blockIdx.x;
  int lane = threadIdx.x;  // 64 threads
  float uv[32];
#pragma unroll
  for (int c = 0; c < 32; ++c) uv[c] = u[(size_t)a * TSEQ + c * 64 + lane];
  unsigned removed = 0;
  int tidx = 0;
#pragma unroll
  for (int r = 0; r < 12; ++r) {
    float best = -1e30f; int bidx = 1 << 30;
#pragma unroll
    for (int c = 0; c < 32; ++c) {
      if (!((removed >> c) & 1u)) {
        float vv = uv[c]; int gi = c * 64 + lane;
        if (vv > best || (vv == best && gi < bidx)) { best = vv; bidx = gi; }
      }
    }
#pragma unroll
    for (int mS = 1; mS < 64; mS <<= 1) {
      float ov = __shfl_xor(best, mS, 64);
      int oi = __shfl_xor(bidx, mS, 64);
      if (ov > best || (ov == best && oi < bidx)) { best = ov; bidx = oi; }
    }
    if (lane == (bidx & 63)) removed |= 1u << (bidx >> 6);
    if (lane == r) tidx = bidx;   // lane r remembers top_idx[r]
  }
  float srow[12];
#pragma unroll
  for (int r = 0; r < 12; ++r) {
    int tr = __shfl(tidx, r, 64);
    srow[r] = (lane < 32) ? S[((size_t)a * TSEQ + tr) * 32 + lane] : 0.f;
  }
  float m = 0.f;
  unsigned blocked = 0;
#pragma unroll
  for (int g = 0; g < 4; ++g) {
    float gains[12];
#pragma unroll
    for (int r = 0; r < 12; ++r) {
      float gr = (lane < 32) ? fmaxf(srow[r] - m, 0.f) : 0.f;
      gains[r] = wsum(gr);
    }
    float best = -1e30f; int bj = 0;
#pragma unroll
    for (int r = 0; r < 12; ++r) {
      float vv = ((blocked >> r) & 1u) ? -1e9f : gains[r];
      if (vv > best) { best = vv; bj = r; }  // first-max
    }
    blocked |= 1u << bj;
#pragma unroll
    for (int r = 0; r < 12; ++r) m = (r == bj) ? fmaxf(m, srow[r]) : m;
    int gidx = __shfl(tidx, bj, 64);
    if (lane == 0) glob[a * 4 + g] = gidx;
  }
}

// ---------------- final 10-candidate attention ----------------
__global__ __launch_bounds__(256) void attend_kernel(
    const float* __restrict__ q, const float* __restrict__ k,
    const float* __restrict__ v, const int* __restrict__ sel,
    const int* __restrict__ glob, float* __restrict__ preout) {
  int wid = blockIdx.x * 4 + (threadIdx.x >> 6);
  int lane = threadIdx.x & 63;
  int bh = wid >> 11, t = wid & (TSEQ - 1);
  int h = bh % NH, b = bh / NH;
  float qv = q[((size_t)bh * TSEQ + t) * HD + lane];
  int cand[10];
  const int* selp = sel + ((size_t)bh * TSEQ + t) * 6;
#pragma unroll
  for (int c = 0; c < 6; ++c) cand[c] = selp[c];
#pragma unroll
  for (int c = 0; c < 4; ++c) cand[6 + c] = glob[h * 4 + c];
  float sc[10];
#pragma unroll
  for (int c = 0; c < 10; ++c) {
    float kv = k[((size_t)bh * TSEQ + cand[c]) * HD + lane];
    sc[c] = wsum(qv * kv);
  }
  float mx = sc[0];
#pragma unroll
  for (int c = 1; c < 10; ++c) mx = fmaxf(mx, sc[c]);
  float e[10], den = 0.f;
#pragma unroll
  for (int c = 0; c < 10; ++c) { e[c] = expf(sc[c] - mx); den += e[c]; }
  float o = 0.f;
#pragma unroll
  for (int c = 0; c < 10; ++c) {
    float w = e[c] / den;
    o += w * v[((size_t)bh * TSEQ + cand[c]) * HD + lane];
  }
  preout[((size_t)b * TSEQ + t) * DM + h * HD + lane] = o;
}

extern "C" void kernel_launch(void* const* d_in, const int* in_sizes, int n_in,
                              void* d_out, int out_size, void* d_ws, size_t ws_size,
                              hipStream_t stream) {
  const float* x  = (const float*)d_in[0];
  const float* Wq = (const float*)d_in[1];
  const float* bq = (const float*)d_in[2];
  const float* Wk = (const float*)d_in[3];
  const float* bk = (const float*)d_in[4];
  const float* Wv = (const float*)d_in[5];
  const float* bv = (const float*)d_in[6];
  const float* Wo = (const float*)d_in[7];
  const float* bo = (const float*)d_in[8];
  float* out = (float*)d_out;

  float* ws = (float*)d_ws;
  const size_t QKV = (size_t)NBH * TSEQ * HD;  // 3145728
  float* qb = ws;
  float* kb = qb + QKV;
  float* vb = kb + QKV;
  float* preout = vb + QKV;                    // 3145728 floats
  float* Qp = preout + QKV;
  float* S  = Qp + (size_t)NH * 32 * HD;       // 24576
  float* u  = S + (size_t)NH * TSEQ * 32;      // 786432
  int* sel  = (int*)(u + (size_t)NH * TSEQ);   // 24576
  int* glob = sel + (size_t)NBH * TSEQ * 6;    // 294912 ints

  qk_kernel<<<dim3(6, 32, 2), 256, 0, stream>>>(x, Wq, bq, qb, Wk, bk, kb);
  v_kernel<<<dim3(6, 32), 256, 0, stream>>>(x, Wv, bv, vb);
  window_kernel<<<12288, 256, 0, stream>>>(qb, kb, sel);
  qp_kernel<<<96, 256, 0, stream>>>(qb, Qp);
  proto_score_kernel<<<dim3(512, NH), 256, 0, stream>>>(kb, Qp, S, u);
  head_select_kernel<<<NH, 64, 0, stream>>>(u, S, glob);
  attend_kernel<<<12288, 256, 0, stream>>>(qb, kb, vb, sel, glob, preout);
  oproj_kernel<<<dim3(6, 32), 256, 0, stream>>>(preout, Wo, bo, out);
}

// Round 6
// 302.994 us; speedup vs baseline: 1.7274x; 1.2438x over previous
//
#include <hip/hip_runtime.h>
#include <math.h>

#define TSEQ 2048
#define DM   768
#define NH   12
#define HD   64
#define NBH  24

typedef __attribute__((ext_vector_type(8))) short short8;
typedef __attribute__((ext_vector_type(4))) float f32x4;

#define MFMA_BF16(a, b, c) __builtin_amdgcn_mfma_f32_16x16x32_bf16(a, b, c, 0, 0, 0)

// round(linspace(0, 2047, 32)) — verified against fp32 evaluation (no .5 ties)
__constant__ int c_idxp[32] = {0,66,132,198,264,330,396,462,528,594,660,726,
  792,858,924,990,1057,1123,1189,1255,1321,1387,1453,1519,1585,1651,1717,1783,
  1849,1915,1981,2047};

// ---- DPP helpers: row(16-lane)-local rotations on the VALU pipe ----
template <int CTRL>
__device__ __forceinline__ float dppf(float x) {
  return __int_as_float(__builtin_amdgcn_mov_dpp(__float_as_int(x), CTRL, 0xF, 0xF, true));
}
template <int CTRL>
__device__ __forceinline__ int dppi(int x) {
  return __builtin_amdgcn_mov_dpp(x, CTRL, 0xF, 0xF, true);
}
// full 64-lane sum: 4 DPP rotations (row-local) + 2 cross-row shuffles
__device__ __forceinline__ float wsum(float v) {
  v += dppf<0x121>(v);  // row_ror:1
  v += dppf<0x122>(v);  // row_ror:2
  v += dppf<0x124>(v);  // row_ror:4
  v += dppf<0x128>(v);  // row_ror:8
  v += __shfl_xor(v, 16, 64);
  v += __shfl_xor(v, 32, 64);
  return v;
}
__device__ __forceinline__ float wmaxr(float v) {
  v = fmaxf(v, dppf<0x121>(v));
  v = fmaxf(v, dppf<0x122>(v));
  v = fmaxf(v, dppf<0x124>(v));
  v = fmaxf(v, dppf<0x128>(v));
  v = fmaxf(v, __shfl_xor(v, 16, 64));
  v = fmaxf(v, __shfl_xor(v, 32, 64));
  return v;
}

__device__ __forceinline__ ushort bf16rne(float x) {
  unsigned u = __float_as_uint(x);
  return (ushort)((u + 0x7fffu + ((u >> 16) & 1u)) >> 16);
}

// split 8 fp32 -> bf16 h/m/l (RNE each stage; subtractions exact)
template <bool NEED_L>
__device__ __forceinline__ void split_store(const float4& v0, const float4& v1,
                                            ushort* ph, ushort* pm, ushort* pl) {
  float xs[8] = {v0.x, v0.y, v0.z, v0.w, v1.x, v1.y, v1.z, v1.w};
  short8 h, m, l;
#pragma unroll
  for (int j = 0; j < 8; ++j) {
    float x = xs[j];
    ushort hb = bf16rne(x);
    h[j] = (short)hb;
    float d = x - __uint_as_float((unsigned)hb << 16);
    ushort mb = bf16rne(d);
    m[j] = (short)mb;
    if (NEED_L) {
      float d2 = d - __uint_as_float((unsigned)mb << 16);
      l[j] = (short)bf16rne(d2);
    }
  }
  *(short8*)ph = h;
  *(short8*)pm = m;
  if (NEED_L) *(short8*)pl = l;
}

// ---------------- split-bf16 MFMA GEMM: dst = (A @ B^T + bias) * scale ------
template <int MODE, int NPROD>
__device__ __forceinline__ void gemm_mfma_body(
    const float* __restrict__ A, const float* __restrict__ B,
    const float* __restrict__ bias, float* __restrict__ dst, float scale,
    int mblk, int nblk, ushort* lds) {
  const int tid = threadIdx.x;
  const int lane = tid & 63;
  const int w = tid >> 6;
  const int wr = w >> 1, wc = w & 1;
  const int lrow = lane & 15, kq = lane >> 4;
  constexpr int BUF = 128 * 40;
  ushort* Ahs = lds;
  ushort* Ams = lds + BUF;
  ushort* Als = (NPROD == 6) ? lds + 2 * BUF : nullptr;
  ushort* Bhs = lds + ((NPROD == 6) ? 3 : 2) * BUF;
  ushort* Bms = Bhs + BUF;
  ushort* Bls = (NPROD == 6) ? Bhs + 2 * BUF : nullptr;

  f32x4 acc[4][4];
#pragma unroll
  for (int i = 0; i < 4; ++i)
#pragma unroll
    for (int j = 0; j < 4; ++j) {
      f32x4 z = {0.f, 0.f, 0.f, 0.f};
      acc[i][j] = z;
    }

  float4 pa0[2], pa1[2], pb0[2], pb1[2];
#pragma unroll
  for (int it = 0; it < 2; ++it) {
    int seg = it * 256 + tid, srow = seg >> 2, skq = (seg & 3) * 8;
    pa0[it] = *(const float4*)(A + (size_t)(mblk + srow) * DM + skq);
    pa1[it] = *(const float4*)(A + (size_t)(mblk + srow) * DM + skq + 4);
    pb0[it] = *(const float4*)(B + (size_t)(nblk + srow) * DM + skq);
    pb1[it] = *(const float4*)(B + (size_t)(nblk + srow) * DM + skq + 4);
  }

  for (int k0 = 0; k0 < DM; k0 += 32) {
    __syncthreads();
#pragma unroll
    for (int it = 0; it < 2; ++it) {
      int seg = it * 256 + tid, srow = seg >> 2, skq = (seg & 3) * 8;
      int o = srow * 40 + skq;
      split_store<NPROD == 6>(pa0[it], pa1[it], Ahs + o, Ams + o,
                              (NPROD == 6) ? Als + o : nullptr);
      split_store<NPROD == 6>(pb0[it], pb1[it], Bhs + o, Bms + o,
                              (NPROD == 6) ? Bls + o : nullptr);
    }
    __syncthreads();
    if (k0 + 32 < DM) {
#pragma unroll
      for (int it = 0; it < 2; ++it) {
        int seg = it * 256 + tid, srow = seg >> 2, skq = (seg & 3) * 8;
        pa0[it] = *(const float4*)(A + (size_t)(mblk + srow) * DM + k0 + 32 + skq);
        pa1[it] = *(const float4*)(A + (size_t)(mblk + srow) * DM + k0 + 36 + skq);
        pb0[it] = *(const float4*)(B + (size_t)(nblk + srow) * DM + k0 + 32 + skq);
        pb1[it] = *(const float4*)(B + (size_t)(nblk + srow) * DM + k0 + 36 + skq);
      }
    }
    short8 afh[4], afm[4], afl[4];
#pragma unroll
    for (int fi = 0; fi < 4; ++fi) {
      int o = (wr * 64 + fi * 16 + lrow) * 40 + kq * 8;
      afh[fi] = *(const short8*)&Ahs[o];
      afm[fi] = *(const short8*)&Ams[o];
      if (NPROD == 6) afl[fi] = *(const short8*)&Als[o];
    }
#pragma unroll
    for (int fj = 0; fj < 4; ++fj) {
      int o = (wc * 64 + fj * 16 + lrow) * 40 + kq * 8;
      short8 bfh = *(const short8*)&Bhs[o];
      short8 bfm = *(const short8*)&Bms[o];
      short8 bfl;
      if (NPROD == 6) bfl = *(const short8*)&Bls[o];
#pragma unroll
      for (int fi = 0; fi < 4; ++fi) {
        acc[fi][fj] = MFMA_BF16(afh[fi], bfh, acc[fi][fj]);
        acc[fi][fj] = MFMA_BF16(afm[fi], bfh, acc[fi][fj]);
        acc[fi][fj] = MFMA_BF16(afh[fi], bfm, acc[fi][fj]);
        if (NPROD == 6) {
          acc[fi][fj] = MFMA_BF16(afm[fi], bfm, acc[fi][fj]);
          acc[fi][fj] = MFMA_BF16(afl[fi], bfh, acc[fi][fj]);
          acc[fi][fj] = MFMA_BF16(afh[fi], bfl, acc[fi][fj]);
        }
      }
    }
  }

#pragma unroll
  for (int fj = 0; fj < 4; ++fj) {
    int col = nblk + wc * 64 + fj * 16 + lrow;
    float bv = bias[col];
#pragma unroll
    for (int fi = 0; fi < 4; ++fi) {
#pragma unroll
      for (int reg = 0; reg < 4; ++reg) {
        int row = mblk + wr * 64 + fi * 16 + kq * 4 + reg;
        float o = (acc[fi][fj][reg] + bv) * scale;
        if (MODE == 0) {
          dst[(size_t)row * DM + col] = o;
        } else {
          int b_ = row >> 11, t = row & (TSEQ - 1);
          int h = col >> 6, dd = col & 63;
          dst[(((size_t)(b_ * NH + h)) * TSEQ + t) * HD + dd] = o;
        }
      }
    }
  }
}

__global__ __launch_bounds__(256) void qk_kernel(
    const float* __restrict__ X,
    const float* __restrict__ Wq, const float* __restrict__ bq, float* __restrict__ qd,
    const float* __restrict__ Wk, const float* __restrict__ bk, float* __restrict__ kd) {
  __shared__ ushort lds[6 * 128 * 40];
  int z = blockIdx.z;
  gemm_mfma_body<1, 6>(X, z ? Wk : Wq, z ? bk : bq, z ? kd : qd,
                       z ? 1.0f : 0.125f, blockIdx.y * 128, blockIdx.x * 128, lds);
}

__global__ __launch_bounds__(256) void v_kernel(
    const float* __restrict__ X, const float* __restrict__ Wv,
    const float* __restrict__ bv, float* __restrict__ vd) {
  __shared__ ushort lds[4 * 128 * 40];
  gemm_mfma_body<1, 3>(X, Wv, bv, vd, 1.0f, blockIdx.y * 128, blockIdx.x * 128, lds);
}

__global__ __launch_bounds__(256) void oproj_kernel(
    const float* __restrict__ X, const float* __restrict__ W,
    const float* __restrict__ bias, float* __restrict__ dst) {
  __shared__ ushort lds[4 * 128 * 40];
  gemm_mfma_body<0, 3>(X, W, bias, dst, 1.0f, blockIdx.y * 128, blockIdx.x * 128, lds);
}

// ---------------- window selection: one wave per (bh, t) ----------------
// lane = kq*16 + f: fragment f in [0,16) (lane&15), dim-quarter kq (lane>>4)
// holding dims [kq*8, kq*8+8) and [32+kq*8, 32+kq*8+8) (MFMA frag layout).
// Cosine Gram matrix G = Kn·Kn^T computed once via 12 split-bf16 MFMAs;
// per-round penalty = 1 bpermute. Argmax via DPP row rotations (VALU pipe).
__global__ __launch_bounds__(256) void window_kernel(
    const float* __restrict__ q, const float* __restrict__ k,
    int* __restrict__ sel) {
  int wid = blockIdx.x * 4 + (threadIdx.x >> 6);
  int lane = threadIdx.x & 63;
  int f = lane & 15, kq = lane >> 4;
  int bh = wid >> 11, t = wid & (TSEQ - 1);
  int start = t - 8;
  if (start < 0) start = 0;
  if (start > TSEQ - 16) start = TSEQ - 16;

  const float* kp = k + ((size_t)bh * TSEQ + start + f) * HD + kq * 8;
  const float* qp = q + ((size_t)bh * TSEQ + t) * HD + kq * 8;
  float kv[16], qv[16];
  *(float4*)&kv[0]  = *(const float4*)(kp + 0);
  *(float4*)&kv[4]  = *(const float4*)(kp + 4);
  *(float4*)&kv[8]  = *(const float4*)(kp + 32);
  *(float4*)&kv[12] = *(const float4*)(kp + 36);
  *(float4*)&qv[0]  = *(const float4*)(qp + 0);
  *(float4*)&qv[4]  = *(const float4*)(qp + 4);
  *(float4*)&qv[8]  = *(const float4*)(qp + 32);
  *(float4*)&qv[12] = *(const float4*)(qp + 36);

  float sp = 0.f, np = 0.f;
#pragma unroll
  for (int i = 0; i < 16; ++i) { sp = fmaf(qv[i], kv[i], sp); np = fmaf(kv[i], kv[i], np); }
  sp += __shfl_xor(sp, 16, 64); sp += __shfl_xor(sp, 32, 64);
  np += __shfl_xor(np, 16, 64); np += __shfl_xor(np, 32, 64);
  float nrm = fmaxf(sqrtf(np), 1e-6f);
  float kn[16];
#pragma unroll
  for (int i = 0; i < 16; ++i) kn[i] = kv[i] / nrm;  // exact div, as reference

  // split kn into bf16 h/m/l fragments (two K=32 halves)
  short8 h0, m0, l0, h1, m1, l1;
#pragma unroll
  for (int j = 0; j < 8; ++j) {
    float x = kn[j];
    ushort hb = bf16rne(x); h0[j] = (short)hb;
    float d = x - __uint_as_float((unsigned)hb << 16);
    ushort mb = bf16rne(d); m0[j] = (short)mb;
    l0[j] = (short)bf16rne(d - __uint_as_float((unsigned)mb << 16));
    x = kn[8 + j];
    hb = bf16rne(x); h1[j] = (short)hb;
    d = x - __uint_as_float((unsigned)hb << 16);
    mb = bf16rne(d); m1[j] = (short)mb;
    l1[j] = (short)bf16rne(d - __uint_as_float((unsigned)mb << 16));
  }
  // Gram: G[row=kq*4+reg][col=f] in g[reg] (6-product split, err ~1e-7)
  f32x4 g = {0.f, 0.f, 0.f, 0.f};
  g = MFMA_BF16(h0, h0, g); g = MFMA_BF16(h1, h1, g);
  g = MFMA_BF16(m0, h0, g); g = MFMA_BF16(m1, h1, g);
  g = MFMA_BF16(h0, m0, g); g = MFMA_BF16(h1, m1, g);
  g = MFMA_BF16(m0, m0, g); g = MFMA_BF16(m1, m1, g);
  g = MFMA_BF16(l0, h0, g); g = MFMA_BF16(l1, h1, g);
  g = MFMA_BF16(h0, l0, g); g = MFMA_BF16(h1, l1, g);

  int dist = start + f - t; if (dist < 0) dist = -dist;
  float tmp = sp + 0.2f * expf(-(float)dist * 0.125f);

  int* selp = sel + ((size_t)bh * TSEQ + t) * 6;
#pragma unroll
  for (int r = 0; r < 6; ++r) {
    // row-local argmax over f (first-max tie-break), DPP rotations
    float best = tmp; int bj = f;
    {
      float ov = dppf<0x121>(best); int oi = dppi<0x121>(bj);
      if (ov > best || (ov == best && oi < bj)) { best = ov; bj = oi; }
      ov = dppf<0x122>(best); oi = dppi<0x122>(bj);
      if (ov > best || (ov == best && oi < bj)) { best = ov; bj = oi; }
      ov = dppf<0x124>(best); oi = dppi<0x124>(bj);
      if (ov > best || (ov == best && oi < bj)) { best = ov; bj = oi; }
      ov = dppf<0x128>(best); oi = dppi<0x128>(bj);
      if (ov > best || (ov == best && oi < bj)) { best = ov; bj = oi; }
    }
    if (lane == 0) selp[r] = start + bj;
    if (r < 5) {
      // G[bj][f]: reg bj&3 of lane ((bj>>2)*16 + f)
      float s01 = (bj & 1) ? g[1] : g[0];
      float s23 = (bj & 1) ? g[3] : g[2];
      float gsel = (bj & 2) ? s23 : s01;
      float grow = __shfl(gsel, ((bj >> 2) << 4) | f, 64);
      tmp -= 0.2f * fmaxf(grow, 0.f);  // penalty before masking (ref order)
    }
    if (f == bj) tmp = -1e9f;
  }
}

// ---------------- prototype queries Qp[a][p][:] ----------------
__global__ __launch_bounds__(256) void qp_kernel(const float* __restrict__ q,
                                                 float* __restrict__ Qp) {
  int wid = blockIdx.x * 4 + (threadIdx.x >> 6);  // 0..383
  int lane = threadIdx.x & 63;
  int a = wid >> 5, p = wid & 31;
  int t = c_idxp[p];
  float v = 0.5f * (q[((size_t)(2 * a) * TSEQ + t) * HD + lane] +
                    q[((size_t)(2 * a + 1) * TSEQ + t) * HD + lane]);
  float n2 = wsum(v * v);
  float nrm = fmaxf(sqrtf(n2), 1e-6f);
  Qp[((size_t)a * 32 + p) * HD + lane] = v / nrm;
}

// ---------------- S[a][t][p] and u[a][t] ----------------
__global__ __launch_bounds__(256) void proto_score_kernel(
    const float* __restrict__ k, const float* __restrict__ Qp,
    float* __restrict__ S, float* __restrict__ u) {
  int a = blockIdx.y;
  __shared__ float Qs[2048];
  for (int i = threadIdx.x; i < 2048; i += 256) Qs[i] = Qp[(size_t)a * 2048 + i];
  __syncthreads();
  int w = threadIdx.x >> 6, lane = threadIdx.x & 63;
  int t = blockIdx.x * 4 + w;
  float km = 0.5f * (k[((size_t)(2 * a) * TSEQ + t) * HD + lane] +
                     k[((size_t)(2 * a + 1) * TSEQ + t) * HD + lane]);
  float n2 = wsum(km * km);
  float nrm = fmaxf(sqrtf(n2), 1e-6f);
  float kb = km / nrm;
  float sval = 0.f;
#pragma unroll
  for (int p = 0; p < 32; ++p) {
    float dg = wsum(kb * Qs[p * 64 + lane]);
    dg = fmaxf(dg, 0.f);               // relu
    sval = (lane == p) ? dg : sval;    // lane p keeps S_p
  }
  if (lane < 32) S[((size_t)a * TSEQ + t) * 32 + lane] = sval;
  float x = (lane < 32) ? sval : 0.f;
  float mean = wsum(x) / 32.0f;
  float mx = wmaxr((lane < 32) ? sval : -1e30f);
  float cur = (lane < 32) ? sval : -1e30f;
  float topsum = 0.f;
#pragma unroll
  for (int r = 0; r < 6; ++r) {        // top-6 values (remove one instance each)
    float m = wmaxr(cur);
    topsum += m;
    unsigned long long ball = __ballot(cur == m);
    int first = __ffsll(ball) - 1;
    if (lane == first) cur = -1e30f;
  }
  float dev = (lane < 32) ? (sval - mean) : 0.f;
  float sd = sqrtf(wsum(dev * dev) / 31.0f);  // ddof=1
  float uval = ((1.0f * mean + 0.6f * mx) + 0.4f * (topsum / 6.0f)) + 0.2f * sd;
  if (lane == 0) u[(size_t)a * TSEQ + t] = uval;
}

// ---------------- per-head top-12 + greedy facility location ----------------
__global__ void head_select_kernel(const float* __restrict__ u,
                                   const float* __restrict__ S,
                                   int* __restrict__ glob) {
  int a = blockIdx.x;
  int lane = threadIdx.x;  // 64 threads
  float uv[32];
#pragma unroll
  for (int c = 0; c < 32; ++c) uv[c] = u[(size_t)a * TSEQ + c * 64 + lane];
  unsigned removed = 0;
  int tidx = 0;
#pragma unroll
  for (int r = 0; r < 12; ++r) {
    float best = -1e30f; int bidx = 1 << 30;
#pragma unroll
    for (int c = 0; c < 32; ++c) {
      if (!((removed >> c) & 1u)) {
        float vv = uv[c]; int gi = c * 64 + lane;
        if (vv > best || (vv == best && gi < bidx)) { best = vv; bidx = gi; }
      }
    }
#pragma unroll
    for (int mS = 1; mS < 64; mS <<= 1) {
      float ov = __shfl_xor(best, mS, 64);
      int oi = __shfl_xor(bidx, mS, 64);
      if (ov > best || (ov == best && oi < bidx)) { best = ov; bidx = oi; }
    }
    if (lane == (bidx & 63)) removed |= 1u << (bidx >> 6);
    if (lane == r) tidx = bidx;   // lane r remembers top_idx[r]
  }
  float srow[12];
#pragma unroll
  for (int r = 0; r < 12; ++r) {
    int tr = __shfl(tidx, r, 64);
    srow[r] = (lane < 32) ? S[((size_t)a * TSEQ + tr) * 32 + lane] : 0.f;
  }
  float m = 0.f;
  unsigned blocked = 0;
#pragma unroll
  for (int g = 0; g < 4; ++g) {
    float gains[12];
#pragma unroll
    for (int r = 0; r < 12; ++r) {
      float gr = (lane < 32) ? fmaxf(srow[r] - m, 0.f) : 0.f;
      gains[r] = wsum(gr);
    }
    float best = -1e30f; int bj = 0;
#pragma unroll
    for (int r = 0; r < 12; ++r) {
      float vv = ((blocked >> r) & 1u) ? -1e9f : gains[r];
      if (vv > best) { best = vv; bj = r; }  // first-max
    }
    blocked |= 1u << bj;
#pragma unroll
    for (int r = 0; r < 12; ++r) m = (r == bj) ? fmaxf(m, srow[r]) : m;
    int gidx = __shfl(tidx, bj, 64);
    if (lane == 0) glob[a * 4 + g] = gidx;
  }
}

// ---------------- final 10-candidate attention ----------------
__global__ __launch_bounds__(256) void attend_kernel(
    const float* __restrict__ q, const float* __restrict__ k,
    const float* __restrict__ v, const int* __restrict__ sel,
    const int* __restrict__ glob, float* __restrict__ preout) {
  int wid = blockIdx.x * 4 + (threadIdx.x >> 6);
  int lane = threadIdx.x & 63;
  int bh = wid >> 11, t = wid & (TSEQ - 1);
  int h = bh % NH, b = bh / NH;
  float qv = q[((size_t)bh * TSEQ + t) * HD + lane];
  int cand[10];
  const int* selp = sel + ((size_t)bh * TSEQ + t) * 6;
#pragma unroll
  for (int c = 0; c < 6; ++c) cand[c] = selp[c];
#pragma unroll
  for (int c = 0; c < 4; ++c) cand[6 + c] = glob[h * 4 + c];
  float sc[10];
#pragma unroll
  for (int c = 0; c < 10; ++c) {
    float kv = k[((size_t)bh * TSEQ + cand[c]) * HD + lane];
    sc[c] = wsum(qv * kv);
  }
  float mx = sc[0];
#pragma unroll
  for (int c = 1; c < 10; ++c) mx = fmaxf(mx, sc[c]);
  float e[10], den = 0.f;
#pragma unroll
  for (int c = 0; c < 10; ++c) { e[c] = expf(sc[c] - mx); den += e[c]; }
  float o = 0.f;
#pragma unroll
  for (int c = 0; c < 10; ++c) {
    float w = e[c] / den;
    o += w * v[((size_t)bh * TSEQ + cand[c]) * HD + lane];
  }
  preout[((size_t)b * TSEQ + t) * DM + h * HD + lane] = o;
}

extern "C" void kernel_launch(void* const* d_in, const int* in_sizes, int n_in,
                              void* d_out, int out_size, void* d_ws, size_t ws_size,
                              hipStream_t stream) {
  const float* x  = (const float*)d_in[0];
  const float* Wq = (const float*)d_in[1];
  const float* bq = (const float*)d_in[2];
  const float* Wk = (const float*)d_in[3];
  const float* bk = (const float*)d_in[4];
  const float* Wv = (const float*)d_in[5];
  const float* bv = (const float*)d_in[6];
  const float* Wo = (const float*)d_in[7];
  const float* bo = (const float*)d_in[8];
  float* out = (float*)d_out;

  float* ws = (float*)d_ws;
  const size_t QKV = (size_t)NBH * TSEQ * HD;  // 3145728
  float* qb = ws;
  float* kb = qb + QKV;
  float* vb = kb + QKV;
  float* preout = vb + QKV;                    // 3145728 floats
  float* Qp = preout + QKV;
  float* S  = Qp + (size_t)NH * 32 * HD;       // 24576
  float* u  = S + (size_t)NH * TSEQ * 32;      // 786432
  int* sel  = (int*)(u + (size_t)NH * TSEQ);   // 24576
  int* glob = sel + (size_t)NBH * TSEQ * 6;    // 294912 ints

  qk_kernel<<<dim3(6, 32, 2), 256, 0, stream>>>(x, Wq, bq, qb, Wk, bk, kb);
  v_kernel<<<dim3(6, 32), 256, 0, stream>>>(x, Wv, bv, vb);
  window_kernel<<<12288, 256, 0, stream>>>(qb, kb, sel);
  qp_kernel<<<96, 256, 0, stream>>>(qb, Qp);
  proto_score_kernel<<<dim3(512, NH), 256, 0, stream>>>(kb, Qp, S, u);
  head_select_kernel<<<NH, 64, 0, stream>>>(u, S, glob);
  attend_kernel<<<12288, 256, 0, stream>>>(qb, kb, vb, sel, glob, preout);
  oproj_kernel<<<dim3(6, 32), 256, 0, stream>>>(preout, Wo, bo, out);
}

// Round 7
// 281.397 us; speedup vs baseline: 1.8600x; 1.0767x over previous
//
#include <hip/hip_runtime.h>
#include <math.h>

#define TSEQ 2048
#define DM   768
#define NH   12
#define HD   64
#define NBH  24
#define WN   589824  // 768*768

typedef __attribute__((ext_vector_type(8))) short short8;
typedef __attribute__((ext_vector_type(4))) float f32x4;

#define MFMA_BF16(a, b, c) __builtin_amdgcn_mfma_f32_16x16x32_bf16(a, b, c, 0, 0, 0)

// round(linspace(0, 2047, 32)) — verified against fp32 evaluation (no .5 ties)
__constant__ int c_idxp[32] = {0,66,132,198,264,330,396,462,528,594,660,726,
  792,858,924,990,1057,1123,1189,1255,1321,1387,1453,1519,1585,1651,1717,1783,
  1849,1915,1981,2047};

// ---- DPP helpers: row(16-lane)-local rotations on the VALU pipe ----
template <int CTRL>
__device__ __forceinline__ float dppf(float x) {
  return __int_as_float(__builtin_amdgcn_mov_dpp(__float_as_int(x), CTRL, 0xF, 0xF, true));
}
template <int CTRL>
__device__ __forceinline__ int dppi(int x) {
  return __builtin_amdgcn_mov_dpp(x, CTRL, 0xF, 0xF, true);
}
__device__ __forceinline__ float wsum(float v) {
  v += dppf<0x121>(v);
  v += dppf<0x122>(v);
  v += dppf<0x124>(v);
  v += dppf<0x128>(v);
  v += __shfl_xor(v, 16, 64);
  v += __shfl_xor(v, 32, 64);
  return v;
}
__device__ __forceinline__ float wmaxr(float v) {
  v = fmaxf(v, dppf<0x121>(v));
  v = fmaxf(v, dppf<0x122>(v));
  v = fmaxf(v, dppf<0x124>(v));
  v = fmaxf(v, dppf<0x128>(v));
  v = fmaxf(v, __shfl_xor(v, 16, 64));
  v = fmaxf(v, __shfl_xor(v, 32, 64));
  return v;
}

__device__ __forceinline__ ushort bf16rne(float x) {
  unsigned u = __float_as_uint(x);
  return (ushort)((u + 0x7fffu + ((u >> 16) & 1u)) >> 16);
}

// split 8 fp32 -> bf16 h/m/l (RNE each stage; subtractions exact)
template <bool NEED_L>
__device__ __forceinline__ void split_store(const float4& v0, const float4& v1,
                                            ushort* ph, ushort* pm, ushort* pl) {
  float xs[8] = {v0.x, v0.y, v0.z, v0.w, v1.x, v1.y, v1.z, v1.w};
  short8 h, m, l;
#pragma unroll
  for (int j = 0; j < 8; ++j) {
    float x = xs[j];
    ushort hb = bf16rne(x);
    h[j] = (short)hb;
    float d = x - __uint_as_float((unsigned)hb << 16);
    ushort mb = bf16rne(d);
    m[j] = (short)mb;
    if (NEED_L) {
      float d2 = d - __uint_as_float((unsigned)mb << 16);
      l[j] = (short)bf16rne(d2);
    }
  }
  *(short8*)ph = h;
  *(short8*)pm = m;
  if (NEED_L) *(short8*)pl = l;
}

// Swizzled LDS layout: tile stored as 128B lines (64 ushort) of 8 x 16B chunks,
// chunk' = chunk8 ^ (line&7). Conflict-free for both staging writes and
// 16-lane x b128 fragment reads (one lane per bank-quad per line).
__device__ __forceinline__ int lds_idx(int row, int chunk /*0..3*/) {
  int line = row >> 1;
  int c8 = ((row & 1) << 2) | chunk;
  return line * 64 + ((c8 ^ (line & 7)) << 3);
}

// ---------------- W pre-split: out[mi][lvl][WN], lvl in {h,m,l} -------------
__global__ __launch_bounds__(256) void convertW_kernel(
    const float* __restrict__ W0, const float* __restrict__ W1,
    const float* __restrict__ W2, const float* __restrict__ W3,
    ushort* __restrict__ out) {
  int mi = blockIdx.y;
  const float* s = (mi == 0) ? W0 : (mi == 1) ? W1 : (mi == 2) ? W2 : W3;
  size_t base = (size_t)(blockIdx.x * 256 + threadIdx.x) * 8;
  ushort* h = out + (size_t)mi * 3 * WN;
  float4 v0 = *(const float4*)(s + base);
  float4 v1 = *(const float4*)(s + base + 4);
  split_store<true>(v0, v1, h + base, h + WN + base, h + 2 * WN + base);
}

// ---------------- split-bf16 MFMA GEMM: dst = (A @ B^T + bias) * scale ------
// A [M,768] fp32 (split to bf16 h/m/l during LDS staging, RNE — identical
// math to R5/R6); B pre-split bf16 h/m/l in global. 128x64 tile, BK=32,
// 256 thr = 4 waves (2Mx2N), per wave 4x2 16x16x32 frags.
// Product order per acc element: hh,mh,hm(,mm,lh,hl) — bit-identical to R6.
template <int MODE, int NPROD>
__device__ __forceinline__ void gemm_mfma_body(
    const float* __restrict__ A,
    const ushort* __restrict__ Bh_g, const ushort* __restrict__ Bm_g,
    const ushort* __restrict__ Bl_g,
    const float* __restrict__ bias, float* __restrict__ dst, float scale,
    int mblk, int nblk, ushort* lds) {
  const int tid = threadIdx.x;
  const int lane = tid & 63;
  const int w = tid >> 6;
  const int wr = w >> 1, wc = w & 1;
  const int lrow = lane & 15, kq = lane >> 4;
  constexpr int ABUF = 4096;  // 128 rows x 32 ushort (as 64 lines x 64)
  constexpr int BBUF = 2048;  // 64 rows x 32 ushort
  ushort* Ahs = lds;
  ushort* Ams = Ahs + ABUF;
  ushort* Als = (NPROD == 6) ? (Ams + ABUF) : nullptr;
  ushort* Bhs = (NPROD == 6) ? (lds + 3 * ABUF) : (lds + 2 * ABUF);
  ushort* Bms = Bhs + BBUF;
  ushort* Bls = (NPROD == 6) ? (Bms + BBUF) : nullptr;

  const int arow = tid >> 2;   // 0..63 (and +64 for 2nd segment)
  const int achk = tid & 3;
  const int aoff0 = lds_idx(arow, achk);
  const int aoff1 = lds_idx(arow + 64, achk);
  const int boff = lds_idx(arow, achk);

  const float*  Ap0 = A + (size_t)(mblk + arow) * DM + achk * 8;
  const float*  Ap1 = A + (size_t)(mblk + 64 + arow) * DM + achk * 8;
  const ushort* Bhp = Bh_g + (size_t)(nblk + arow) * DM + achk * 8;
  const ushort* Bmp = Bm_g + (size_t)(nblk + arow) * DM + achk * 8;
  const ushort* Blp = (NPROD == 6) ? (Bl_g + (size_t)(nblk + arow) * DM + achk * 8) : nullptr;

  f32x4 acc[4][2];
#pragma unroll
  for (int i = 0; i < 4; ++i)
#pragma unroll
    for (int j = 0; j < 2; ++j) {
      f32x4 z = {0.f, 0.f, 0.f, 0.f};
      acc[i][j] = z;
    }

  float4 pa00 = *(const float4*)(Ap0 + 0), pa01 = *(const float4*)(Ap0 + 4);
  float4 pa10 = *(const float4*)(Ap1 + 0), pa11 = *(const float4*)(Ap1 + 4);
  short8 pbh = *(const short8*)Bhp;
  short8 pbm = *(const short8*)Bmp;
  short8 pbl;
  if (NPROD == 6) pbl = *(const short8*)Blp;

  for (int k0 = 0; k0 < DM; k0 += 32) {
    __syncthreads();
    split_store<NPROD == 6>(pa00, pa01, Ahs + aoff0, Ams + aoff0,
                            (NPROD == 6) ? Als + aoff0 : (ushort*)nullptr);
    split_store<NPROD == 6>(pa10, pa11, Ahs + aoff1, Ams + aoff1,
                            (NPROD == 6) ? Als + aoff1 : (ushort*)nullptr);
    *(short8*)&Bhs[boff] = pbh;
    *(short8*)&Bms[boff] = pbm;
    if (NPROD == 6) *(short8*)&Bls[boff] = pbl;
    __syncthreads();
    if (k0 + 32 < DM) {  // prefetch next K-tile; overlaps MFMA
      pa00 = *(const float4*)(Ap0 + k0 + 32);
      pa01 = *(const float4*)(Ap0 + k0 + 36);
      pa10 = *(const float4*)(Ap1 + k0 + 32);
      pa11 = *(const float4*)(Ap1 + k0 + 36);
      pbh = *(const short8*)(Bhp + k0 + 32);
      pbm = *(const short8*)(Bmp + k0 + 32);
      if (NPROD == 6) pbl = *(const short8*)(Blp + k0 + 32);
    }
    short8 afh[4], afm[4], afl[4];
#pragma unroll
    for (int fi = 0; fi < 4; ++fi) {
      int o = lds_idx(wr * 64 + fi * 16 + lrow, kq);
      afh[fi] = *(const short8*)&Ahs[o];
      afm[fi] = *(const short8*)&Ams[o];
      if (NPROD == 6) afl[fi] = *(const short8*)&Als[o];
    }
#pragma unroll
    for (int fj = 0; fj < 2; ++fj) {
      int o = lds_idx(wc * 32 + fj * 16 + lrow, kq);
      short8 bfh = *(const short8*)&Bhs[o];
      short8 bfm = *(const short8*)&Bms[o];
      short8 bfl;
      if (NPROD == 6) bfl = *(const short8*)&Bls[o];
#pragma unroll
      for (int fi = 0; fi < 4; ++fi) {
        acc[fi][fj] = MFMA_BF16(afh[fi], bfh, acc[fi][fj]);
        acc[fi][fj] = MFMA_BF16(afm[fi], bfh, acc[fi][fj]);
        acc[fi][fj] = MFMA_BF16(afh[fi], bfm, acc[fi][fj]);
        if (NPROD == 6) {
          acc[fi][fj] = MFMA_BF16(afm[fi], bfm, acc[fi][fj]);
          acc[fi][fj] = MFMA_BF16(afl[fi], bfh, acc[fi][fj]);
          acc[fi][fj] = MFMA_BF16(afh[fi], bfl, acc[fi][fj]);
        }
      }
    }
  }

#pragma unroll
  for (int fj = 0; fj < 2; ++fj) {
    int col = nblk + wc * 32 + fj * 16 + lrow;
    float bv = bias[col];
#pragma unroll
    for (int fi = 0; fi < 4; ++fi) {
#pragma unroll
      for (int reg = 0; reg < 4; ++reg) {
        int row = mblk + wr * 64 + fi * 16 + kq * 4 + reg;
        float o = (acc[fi][fj][reg] + bv) * scale;
        if (MODE == 0) {
          dst[(size_t)row * DM + col] = o;
        } else {
          int b_ = row >> 11, t = row & (TSEQ - 1);
          int h = col >> 6, dd = col & 63;
          dst[(((size_t)(b_ * NH + h)) * TSEQ + t) * HD + dd] = o;
        }
      }
    }
  }
}

__global__ __launch_bounds__(256) void qk_kernel(
    const float* __restrict__ X, const ushort* __restrict__ wsp,
    const float* __restrict__ bq, float* __restrict__ qd,
    const float* __restrict__ bk, float* __restrict__ kd) {
  __shared__ ushort lds[3 * 4096 + 3 * 2048];  // 36 KB
  int mi = blockIdx.z;  // 0 = Wq, 1 = Wk
  const ushort* Bb = wsp + (size_t)mi * 3 * WN;
  gemm_mfma_body<1, 6>(X, Bb, Bb + WN, Bb + 2 * WN,
                       mi ? bk : bq, mi ? kd : qd, mi ? 1.0f : 0.125f,
                       blockIdx.y * 128, blockIdx.x * 64, lds);
}

__global__ __launch_bounds__(256) void v_kernel(
    const float* __restrict__ X, const ushort* __restrict__ wsp,
    const float* __restrict__ bv, float* __restrict__ vd) {
  __shared__ ushort lds[2 * 4096 + 2 * 2048];  // 24 KB
  const ushort* Bb = wsp + (size_t)2 * 3 * WN;
  gemm_mfma_body<1, 3>(X, Bb, Bb + WN, nullptr, bv, vd, 1.0f,
                       blockIdx.y * 128, blockIdx.x * 64, lds);
}

__global__ __launch_bounds__(256) void oproj_kernel(
    const float* __restrict__ X, const ushort* __restrict__ wsp,
    const float* __restrict__ bias, float* __restrict__ dst) {
  __shared__ ushort lds[2 * 4096 + 2 * 2048];
  const ushort* Bb = wsp + (size_t)3 * 3 * WN;
  gemm_mfma_body<0, 3>(X, Bb, Bb + WN, nullptr, bias, dst, 1.0f,
                       blockIdx.y * 128, blockIdx.x * 64, lds);
}

// ---------------- window selection: one wave per (bh, t) ----------------
__global__ __launch_bounds__(256) void window_kernel(
    const float* __restrict__ q, const float* __restrict__ k,
    int* __restrict__ sel) {
  int wid = blockIdx.x * 4 + (threadIdx.x >> 6);
  int lane = threadIdx.x & 63;
  int f = lane & 15, kq = lane >> 4;
  int bh = wid >> 11, t = wid & (TSEQ - 1);
  int start = t - 8;
  if (start < 0) start = 0;
  if (start > TSEQ - 16) start = TSEQ - 16;

  const float* kp = k + ((size_t)bh * TSEQ + start + f) * HD + kq * 8;
  const float* qp = q + ((size_t)bh * TSEQ + t) * HD + kq * 8;
  float kv[16], qv[16];
  *(float4*)&kv[0]  = *(const float4*)(kp + 0);
  *(float4*)&kv[4]  = *(const float4*)(kp + 4);
  *(float4*)&kv[8]  = *(const float4*)(kp + 32);
  *(float4*)&kv[12] = *(const float4*)(kp + 36);
  *(float4*)&qv[0]  = *(const float4*)(qp + 0);
  *(float4*)&qv[4]  = *(const float4*)(qp + 4);
  *(float4*)&qv[8]  = *(const float4*)(qp + 32);
  *(float4*)&qv[12] = *(const float4*)(qp + 36);

  float sp = 0.f, np = 0.f;
#pragma unroll
  for (int i = 0; i < 16; ++i) { sp = fmaf(qv[i], kv[i], sp); np = fmaf(kv[i], kv[i], np); }
  sp += __shfl_xor(sp, 16, 64); sp += __shfl_xor(sp, 32, 64);
  np += __shfl_xor(np, 16, 64); np += __shfl_xor(np, 32, 64);
  float nrm = fmaxf(sqrtf(np), 1e-6f);
  float kn[16];
#pragma unroll
  for (int i = 0; i < 16; ++i) kn[i] = kv[i] / nrm;

  short8 h0, m0, l0, h1, m1, l1;
#pragma unroll
  for (int j = 0; j < 8; ++j) {
    float x = kn[j];
    ushort hb = bf16rne(x); h0[j] = (short)hb;
    float d = x - __uint_as_float((unsigned)hb << 16);
    ushort mb = bf16rne(d); m0[j] = (short)mb;
    l0[j] = (short)bf16rne(d - __uint_as_float((unsigned)mb << 16));
    x = kn[8 + j];
    hb = bf16rne(x); h1[j] = (short)hb;
    d = x - __uint_as_float((unsigned)hb << 16);
    mb = bf16rne(d); m1[j] = (short)mb;
    l1[j] = (short)bf16rne(d - __uint_as_float((unsigned)mb << 16));
  }
  f32x4 g = {0.f, 0.f, 0.f, 0.f};
  g = MFMA_BF16(h0, h0, g); g = MFMA_BF16(h1, h1, g);
  g = MFMA_BF16(m0, h0, g); g = MFMA_BF16(m1, h1, g);
  g = MFMA_BF16(h0, m0, g); g = MFMA_BF16(h1, m1, g);
  g = MFMA_BF16(m0, m0, g); g = MFMA_BF16(m1, m1, g);
  g = MFMA_BF16(l0, h0, g); g = MFMA_BF16(l1, h1, g);
  g = MFMA_BF16(h0, l0, g); g = MFMA_BF16(h1, l1, g);

  int dist = start + f - t; if (dist < 0) dist = -dist;
  float tmp = sp + 0.2f * expf(-(float)dist * 0.125f);

  int* selp = sel + ((size_t)bh * TSEQ + t) * 6;
#pragma unroll
  for (int r = 0; r < 6; ++r) {
    float best = tmp; int bj = f;
    {
      float ov = dppf<0x121>(best); int oi = dppi<0x121>(bj);
      if (ov > best || (ov == best && oi < bj)) { best = ov; bj = oi; }
      ov = dppf<0x122>(best); oi = dppi<0x122>(bj);
      if (ov > best || (ov == best && oi < bj)) { best = ov; bj = oi; }
      ov = dppf<0x124>(best); oi = dppi<0x124>(bj);
      if (ov > best || (ov == best && oi < bj)) { best = ov; bj = oi; }
      ov = dppf<0x128>(best); oi = dppi<0x128>(bj);
      if (ov > best || (ov == best && oi < bj)) { best = ov; bj = oi; }
    }
    if (lane == 0) selp[r] = start + bj;
    if (r < 5) {
      float s01 = (bj & 1) ? g[1] : g[0];
      float s23 = (bj & 1) ? g[3] : g[2];
      float gsel = (bj & 2) ? s23 : s01;
      float grow = __shfl(gsel, ((bj >> 2) << 4) | f, 64);
      tmp -= 0.2f * fmaxf(grow, 0.f);
    }
    if (f == bj) tmp = -1e9f;
  }
}

// ---------------- prototype queries Qp[a][p][:] ----------------
__global__ __launch_bounds__(256) void qp_kernel(const float* __restrict__ q,
                                                 float* __restrict__ Qp) {
  int wid = blockIdx.x * 4 + (threadIdx.x >> 6);
  int lane = threadIdx.x & 63;
  int a = wid >> 5, p = wid & 31;
  int t = c_idxp[p];
  float v = 0.5f * (q[((size_t)(2 * a) * TSEQ + t) * HD + lane] +
                    q[((size_t)(2 * a + 1) * TSEQ + t) * HD + lane]);
  float n2 = wsum(v * v);
  float nrm = fmaxf(sqrtf(n2), 1e-6f);
  Qp[((size_t)a * 32 + p) * HD + lane] = v / nrm;
}

// ---------------- S[a][t][p] and u[a][t] ----------------
__global__ __launch_bounds__(256) void proto_score_kernel(
    const float* __restrict__ k, const float* __restrict__ Qp,
    float* __restrict__ S, float* __restrict__ u) {
  int a = blockIdx.y;
  __shared__ float Qs[2048];
  for (int i = threadIdx.x; i < 2048; i += 256) Qs[i] = Qp[(size_t)a * 2048 + i];
  __syncthreads();
  int w = threadIdx.x >> 6, lane = threadIdx.x & 63;
  int t = blockIdx.x * 4 + w;
  float km = 0.5f * (k[((size_t)(2 * a) * TSEQ + t) * HD + lane] +
                     k[((size_t)(2 * a + 1) * TSEQ + t) * HD + lane]);
  float n2 = wsum(km * km);
  float nrm = fmaxf(sqrtf(n2), 1e-6f);
  float kb = km / nrm;
  float sval = 0.f;
#pragma unroll
  for (int p = 0; p < 32; ++p) {
    float dg = wsum(kb * Qs[p * 64 + lane]);
    dg = fmaxf(dg, 0.f);
    sval = (lane == p) ? dg : sval;
  }
  if (lane < 32) S[((size_t)a * TSEQ + t) * 32 + lane] = sval;
  float x = (lane < 32) ? sval : 0.f;
  float mean = wsum(x) / 32.0f;
  float mx = wmaxr((lane < 32) ? sval : -1e30f);
  float cur = (lane < 32) ? sval : -1e30f;
  float topsum = 0.f;
#pragma unroll
  for (int r = 0; r < 6; ++r) {
    float m = wmaxr(cur);
    topsum += m;
    unsigned long long ball = __ballot(cur == m);
    int first = __ffsll(ball) - 1;
    if (lane == first) cur = -1e30f;
  }
  float dev = (lane < 32) ? (sval - mean) : 0.f;
  float sd = sqrtf(wsum(dev * dev) / 31.0f);
  float uval = ((1.0f * mean + 0.6f * mx) + 0.4f * (topsum / 6.0f)) + 0.2f * sd;
  if (lane == 0) u[(size_t)a * TSEQ + t] = uval;
}

// ---------------- per-head top-12 + greedy facility location ----------------
__global__ void head_select_kernel(const float* __restrict__ u,
                                   const float* __restrict__ S,
                                   int* __restrict__ glob) {
  int a = blockIdx.x;
  int lane = threadIdx.x;
  float uv[32];
#pragma unroll
  for (int c = 0; c < 32; ++c) uv[c] = u[(size_t)a * TSEQ + c * 64 + lane];
  unsigned removed = 0;
  int tidx = 0;
#pragma unroll
  for (int r = 0; r < 12; ++r) {
    float best = -1e30f; int bidx = 1 << 30;
#pragma unroll
    for (int c = 0; c < 32; ++c) {
      if (!((removed >> c) & 1u)) {
        float vv = uv[c]; int gi = c * 64 + lane;
        if (vv > best || (vv == best && gi < bidx)) { best = vv; bidx = gi; }
      }
    }
#pragma unroll
    for (int mS = 1; mS < 64; mS <<= 1) {
      float ov = __shfl_xor(best, mS, 64);
      int oi = __shfl_xor(bidx, mS, 64);
      if (ov > best || (ov == best && oi < bidx)) { best = ov; bidx = oi; }
    }
    if (lane == (bidx & 63)) removed |= 1u << (bidx >> 6);
    if (lane == r) tidx = bidx;
  }
  float srow[12];
#pragma unroll
  for (int r = 0; r < 12; ++r) {
    int tr = __shfl(tidx, r, 64);
    srow[r] = (lane < 32) ? S[((size_t)a * TSEQ + tr) * 32 + lane] : 0.f;
  }
  float m = 0.f;
  unsigned blocked = 0;
#pragma unroll
  for (int g = 0; g < 4; ++g) {
    float gains[12];
#pragma unroll
    for (int r = 0; r < 12; ++r) {
      float gr = (lane < 32) ? fmaxf(srow[r] - m, 0.f) : 0.f;
      gains[r] = wsum(gr);
    }
    float best = -1e30f; int bj = 0;
#pragma unroll
    for (int r = 0; r < 12; ++r) {
      float vv = ((blocked >> r) & 1u) ? -1e9f : gains[r];
      if (vv > best) { best = vv; bj = r; }
    }
    blocked |= 1u << bj;
#pragma unroll
    for (int r = 0; r < 12; ++r) m = (r == bj) ? fmaxf(m, srow[r]) : m;
    int gidx = __shfl(tidx, bj, 64);
    if (lane == 0) glob[a * 4 + g] = gidx;
  }
}

// ---------------- final 10-candidate attention ----------------
__global__ __launch_bounds__(256) void attend_kernel(
    const float* __restrict__ q, const float* __restrict__ k,
    const float* __restrict__ v, const int* __restrict__ sel,
    const int* __restrict__ glob, float* __restrict__ preout) {
  int wid = blockIdx.x * 4 + (threadIdx.x >> 6);
  int lane = threadIdx.x & 63;
  int bh = wid >> 11, t = wid & (TSEQ - 1);
  int h = bh % NH, b = bh / NH;
  float qv = q[((size_t)bh * TSEQ + t) * HD + lane];
  int cand[10];
  const int* selp = sel + ((size_t)bh * TSEQ + t) * 6;
#pragma unroll
  for (int c = 0; c < 6; ++c) cand[c] = selp[c];
#pragma unroll
  for (int c = 0; c < 4; ++c) cand[6 + c] = glob[h * 4 + c];
  float sc[10];
#pragma unroll
  for (int c = 0; c < 10; ++c) {
    float kv = k[((size_t)bh * TSEQ + cand[c]) * HD + lane];
    sc[c] = wsum(qv * kv);
  }
  float mx = sc[0];
#pragma unroll
  for (int c = 1; c < 10; ++c) mx = fmaxf(mx, sc[c]);
  float e[10], den = 0.f;
#pragma unroll
  for (int c = 0; c < 10; ++c) { e[c] = expf(sc[c] - mx); den += e[c]; }
  float o = 0.f;
#pragma unroll
  for (int c = 0; c < 10; ++c) {
    float w = e[c] / den;
    o += w * v[((size_t)bh * TSEQ + cand[c]) * HD + lane];
  }
  preout[((size_t)b * TSEQ + t) * DM + h * HD + lane] = o;
}

extern "C" void kernel_launch(void* const* d_in, const int* in_sizes, int n_in,
                              void* d_out, int out_size, void* d_ws, size_t ws_size,
                              hipStream_t stream) {
  const float* x  = (const float*)d_in[0];
  const float* Wq = (const float*)d_in[1];
  const float* bq = (const float*)d_in[2];
  const float* Wk = (const float*)d_in[3];
  const float* bk = (const float*)d_in[4];
  const float* Wv = (const float*)d_in[5];
  const float* bv = (const float*)d_in[6];
  const float* Wo = (const float*)d_in[7];
  const float* bo = (const float*)d_in[8];
  float* out = (float*)d_out;

  float* ws = (float*)d_ws;
  const size_t QKV = (size_t)NBH * TSEQ * HD;  // 3145728
  float* qb = ws;
  float* kb = qb + QKV;
  float* vb = kb + QKV;
  float* preout = vb + QKV;
  float* Qp = preout + QKV;
  float* S  = Qp + (size_t)NH * 32 * HD;
  float* u  = S + (size_t)NH * TSEQ * 32;
  int* sel  = (int*)(u + (size_t)NH * TSEQ);
  int* glob = sel + (size_t)NBH * TSEQ * 6;
  ushort* wsp = (ushort*)(glob + 64);          // 12 x WN ushorts = 14.16 MB

  convertW_kernel<<<dim3(288, 4), 256, 0, stream>>>(Wq, Wk, Wv, Wo, wsp);
  qk_kernel<<<dim3(12, 32, 2), 256, 0, stream>>>(x, wsp, bq, qb, bk, kb);
  v_kernel<<<dim3(12, 32), 256, 0, stream>>>(x, wsp, bv, vb);
  window_kernel<<<12288, 256, 0, stream>>>(qb, kb, sel);
  qp_kernel<<<96, 256, 0, stream>>>(qb, Qp);
  proto_score_kernel<<<dim3(512, NH), 256, 0, stream>>>(kb, Qp, S, u);
  head_select_kernel<<<NH, 64, 0, stream>>>(u, S, glob);
  attend_kernel<<<12288, 256, 0, stream>>>(qb, kb, vb, sel, glob, preout);
  oproj_kernel<<<dim3(12, 32), 256, 0, stream>>>(preout, wsp, bo, out);
}

// Round 8
// 278.347 us; speedup vs baseline: 1.8804x; 1.0110x over previous
//
#include <hip/hip_runtime.h>
#include <math.h>

#define TSEQ 2048
#define DM   768
#define NH   12
#define HD   64
#define NBH  24
#define WN   589824  // 768*768

typedef __attribute__((ext_vector_type(8))) short short8;
typedef __attribute__((ext_vector_type(4))) float f32x4;

#define MFMA_BF16(a, b, c) __builtin_amdgcn_mfma_f32_16x16x32_bf16(a, b, c, 0, 0, 0)

// round(linspace(0, 2047, 32)) — verified against fp32 evaluation (no .5 ties)
__constant__ int c_idxp[32] = {0,66,132,198,264,330,396,462,528,594,660,726,
  792,858,924,990,1057,1123,1189,1255,1321,1387,1453,1519,1585,1651,1717,1783,
  1849,1915,1981,2047};

// ---- DPP helpers: row(16-lane)-local rotations on the VALU pipe ----
template <int CTRL>
__device__ __forceinline__ float dppf(float x) {
  return __int_as_float(__builtin_amdgcn_mov_dpp(__float_as_int(x), CTRL, 0xF, 0xF, true));
}
template <int CTRL>
__device__ __forceinline__ int dppi(int x) {
  return __builtin_amdgcn_mov_dpp(x, CTRL, 0xF, 0xF, true);
}
__device__ __forceinline__ float wsum(float v) {
  v += dppf<0x121>(v);
  v += dppf<0x122>(v);
  v += dppf<0x124>(v);
  v += dppf<0x128>(v);
  v += __shfl_xor(v, 16, 64);
  v += __shfl_xor(v, 32, 64);
  return v;
}
__device__ __forceinline__ float wmaxr(float v) {
  v = fmaxf(v, dppf<0x121>(v));
  v = fmaxf(v, dppf<0x122>(v));
  v = fmaxf(v, dppf<0x124>(v));
  v = fmaxf(v, dppf<0x128>(v));
  v = fmaxf(v, __shfl_xor(v, 16, 64));
  v = fmaxf(v, __shfl_xor(v, 32, 64));
  return v;
}

__device__ __forceinline__ ushort bf16rne(float x) {
  unsigned u = __float_as_uint(x);
  return (ushort)((u + 0x7fffu + ((u >> 16) & 1u)) >> 16);
}

// split 8 fp32 -> bf16 h/m/l (RNE each stage; subtractions exact)
template <bool NEED_L>
__device__ __forceinline__ void split_store(const float4& v0, const float4& v1,
                                            ushort* ph, ushort* pm, ushort* pl) {
  float xs[8] = {v0.x, v0.y, v0.z, v0.w, v1.x, v1.y, v1.z, v1.w};
  short8 h, m, l;
#pragma unroll
  for (int j = 0; j < 8; ++j) {
    float x = xs[j];
    ushort hb = bf16rne(x);
    h[j] = (short)hb;
    float d = x - __uint_as_float((unsigned)hb << 16);
    ushort mb = bf16rne(d);
    m[j] = (short)mb;
    if (NEED_L) {
      float d2 = d - __uint_as_float((unsigned)mb << 16);
      l[j] = (short)bf16rne(d2);
    }
  }
  *(short8*)ph = h;
  *(short8*)pm = m;
  if (NEED_L) *(short8*)pl = l;
}

// Swizzled LDS layout: tile stored as 128B lines (64 ushort) of 8 x 16B chunks,
// chunk' = chunk8 ^ (line&7). Conflict-free for staging writes and
// 16-lane x b128 fragment reads (one lane per bank-quad per line).
__device__ __forceinline__ int lds_idx(int row, int chunk /*0..3*/) {
  int line = row >> 1;
  int c8 = ((row & 1) << 2) | chunk;
  return line * 64 + ((c8 ^ (line & 7)) << 3);
}

// -------- pre-split: z=0 X -> Xh/Xm/Xl, z=1..4 W -> wsp[mi][lvl][WN] --------
__global__ __launch_bounds__(256) void convert_kernel(
    const float* __restrict__ x,
    const float* __restrict__ W0, const float* __restrict__ W1,
    const float* __restrict__ W2, const float* __restrict__ W3,
    ushort* __restrict__ Xh, ushort* __restrict__ Xm, ushort* __restrict__ Xl,
    ushort* __restrict__ wsp) {
  int z = blockIdx.y;
  size_t base = (size_t)(blockIdx.x * 256 + threadIdx.x) * 8;
  if (z == 0) {
    float4 v0 = *(const float4*)(x + base);
    float4 v1 = *(const float4*)(x + base + 4);
    split_store<true>(v0, v1, Xh + base, Xm + base, Xl + base);
  } else {
    if (base >= WN) return;
    int mi = z - 1;
    const float* s = (mi == 0) ? W0 : (mi == 1) ? W1 : (mi == 2) ? W2 : W3;
    ushort* h = wsp + (size_t)mi * 3 * WN;
    float4 v0 = *(const float4*)(s + base);
    float4 v1 = *(const float4*)(s + base + 4);
    split_store<true>(v0, v1, h + base, h + WN + base, h + 2 * WN + base);
  }
}

// ---------------- split-bf16 MFMA GEMM: dst = (A @ B^T + bias) * scale ------
// A and B both pre-split bf16 h/m/l in global (staging = pure short8 copies).
// 128x64 tile, BK=32, 256 thr = 4 waves (2Mx2N), per wave 4x2 16x16x32 frags.
// Product order per acc element: hh,mh,hm(,mm,lh,hl) — bit-identical to R7.
template <int MODE, int NPROD>
__device__ __forceinline__ void gemm_mfma_body(
    const ushort* __restrict__ Agh, const ushort* __restrict__ Agm,
    const ushort* __restrict__ Agl,
    const ushort* __restrict__ Bgh, const ushort* __restrict__ Bgm,
    const ushort* __restrict__ Bgl,
    const float* __restrict__ bias, float* __restrict__ dst, float scale,
    int mblk, int nblk, ushort* lds) {
  const int tid = threadIdx.x;
  const int lane = tid & 63;
  const int w = tid >> 6;
  const int wr = w >> 1, wc = w & 1;
  const int lrow = lane & 15, kq = lane >> 4;
  constexpr int ABUF = 4096;  // 128 rows x 32 ushort (64 lines x 64)
  constexpr int BBUF = 2048;  // 64 rows x 32 ushort
  ushort* Ahs = lds;
  ushort* Ams = Ahs + ABUF;
  ushort* Als = (NPROD == 6) ? (Ams + ABUF) : nullptr;
  ushort* Bhs = (NPROD == 6) ? (lds + 3 * ABUF) : (lds + 2 * ABUF);
  ushort* Bms = Bhs + BBUF;
  ushort* Bls = (NPROD == 6) ? (Bms + BBUF) : nullptr;

  const int arow = tid >> 2;   // 0..63 (and +64 for 2nd A segment)
  const int achk = tid & 3;
  const int aoff0 = lds_idx(arow, achk);
  const int aoff1 = lds_idx(arow + 64, achk);
  const int boff = lds_idx(arow, achk);

  const size_t a0 = (size_t)(mblk + arow) * DM + achk * 8;
  const size_t a1 = (size_t)(mblk + 64 + arow) * DM + achk * 8;
  const size_t b0 = (size_t)(nblk + arow) * DM + achk * 8;

  f32x4 acc[4][2];
#pragma unroll
  for (int i = 0; i < 4; ++i)
#pragma unroll
    for (int j = 0; j < 2; ++j) {
      f32x4 z = {0.f, 0.f, 0.f, 0.f};
      acc[i][j] = z;
    }

  short8 pah0 = *(const short8*)(Agh + a0), pah1 = *(const short8*)(Agh + a1);
  short8 pam0 = *(const short8*)(Agm + a0), pam1 = *(const short8*)(Agm + a1);
  short8 pal0, pal1;
  if (NPROD == 6) { pal0 = *(const short8*)(Agl + a0); pal1 = *(const short8*)(Agl + a1); }
  short8 pbh = *(const short8*)(Bgh + b0);
  short8 pbm = *(const short8*)(Bgm + b0);
  short8 pbl;
  if (NPROD == 6) pbl = *(const short8*)(Bgl + b0);

  for (int k0 = 0; k0 < DM; k0 += 32) {
    __syncthreads();
    *(short8*)&Ahs[aoff0] = pah0; *(short8*)&Ahs[aoff1] = pah1;
    *(short8*)&Ams[aoff0] = pam0; *(short8*)&Ams[aoff1] = pam1;
    if (NPROD == 6) { *(short8*)&Als[aoff0] = pal0; *(short8*)&Als[aoff1] = pal1; }
    *(short8*)&Bhs[boff] = pbh;
    *(short8*)&Bms[boff] = pbm;
    if (NPROD == 6) *(short8*)&Bls[boff] = pbl;
    __syncthreads();
    if (k0 + 32 < DM) {  // prefetch next K-tile; overlaps MFMA
      pah0 = *(const short8*)(Agh + a0 + k0 + 32);
      pah1 = *(const short8*)(Agh + a1 + k0 + 32);
      pam0 = *(const short8*)(Agm + a0 + k0 + 32);
      pam1 = *(const short8*)(Agm + a1 + k0 + 32);
      if (NPROD == 6) {
        pal0 = *(const short8*)(Agl + a0 + k0 + 32);
        pal1 = *(const short8*)(Agl + a1 + k0 + 32);
      }
      pbh = *(const short8*)(Bgh + b0 + k0 + 32);
      pbm = *(const short8*)(Bgm + b0 + k0 + 32);
      if (NPROD == 6) pbl = *(const short8*)(Bgl + b0 + k0 + 32);
    }
    short8 afh[4], afm[4], afl[4];
#pragma unroll
    for (int fi = 0; fi < 4; ++fi) {
      int o = lds_idx(wr * 64 + fi * 16 + lrow, kq);
      afh[fi] = *(const short8*)&Ahs[o];
      afm[fi] = *(const short8*)&Ams[o];
      if (NPROD == 6) afl[fi] = *(const short8*)&Als[o];
    }
#pragma unroll
    for (int fj = 0; fj < 2; ++fj) {
      int o = lds_idx(wc * 32 + fj * 16 + lrow, kq);
      short8 bfh = *(const short8*)&Bhs[o];
      short8 bfm = *(const short8*)&Bms[o];
      short8 bfl;
      if (NPROD == 6) bfl = *(const short8*)&Bls[o];
#pragma unroll
      for (int fi = 0; fi < 4; ++fi) {
        acc[fi][fj] = MFMA_BF16(afh[fi], bfh, acc[fi][fj]);
        acc[fi][fj] = MFMA_BF16(afm[fi], bfh, acc[fi][fj]);
        acc[fi][fj] = MFMA_BF16(afh[fi], bfm, acc[fi][fj]);
        if (NPROD == 6) {
          acc[fi][fj] = MFMA_BF16(afm[fi], bfm, acc[fi][fj]);
          acc[fi][fj] = MFMA_BF16(afl[fi], bfh, acc[fi][fj]);
          acc[fi][fj] = MFMA_BF16(afh[fi], bfl, acc[fi][fj]);
        }
      }
    }
  }

#pragma unroll
  for (int fj = 0; fj < 2; ++fj) {
    int col = nblk + wc * 32 + fj * 16 + lrow;
    float bv = bias[col];
#pragma unroll
    for (int fi = 0; fi < 4; ++fi) {
#pragma unroll
      for (int reg = 0; reg < 4; ++reg) {
        int row = mblk + wr * 64 + fi * 16 + kq * 4 + reg;
        float o = (acc[fi][fj][reg] + bv) * scale;
        if (MODE == 0) {
          dst[(size_t)row * DM + col] = o;
        } else {
          int b_ = row >> 11, t = row & (TSEQ - 1);
          int h = col >> 6, dd = col & 63;
          dst[(((size_t)(b_ * NH + h)) * TSEQ + t) * HD + dd] = o;
        }
      }
    }
  }
}

// merged q/k/v projection: z = 0 (q, NPROD6), 1 (k, NPROD6), 2 (v, NPROD3)
__global__ __launch_bounds__(256) void qkv_kernel(
    const ushort* __restrict__ Xh, const ushort* __restrict__ Xm,
    const ushort* __restrict__ Xl, const ushort* __restrict__ wsp,
    const float* __restrict__ bq, float* __restrict__ qd,
    const float* __restrict__ bk, float* __restrict__ kd,
    const float* __restrict__ bv, float* __restrict__ vd) {
  __shared__ ushort lds[3 * 4096 + 3 * 2048];  // 36 KB (max of both paths)
  int z = blockIdx.z;
  const ushort* Bb = wsp + (size_t)z * 3 * WN;
  if (z == 2) {
    gemm_mfma_body<1, 3>(Xh, Xm, nullptr, Bb, Bb + WN, nullptr,
                         bv, vd, 1.0f, blockIdx.y * 128, blockIdx.x * 64, lds);
  } else {
    gemm_mfma_body<1, 6>(Xh, Xm, Xl, Bb, Bb + WN, Bb + 2 * WN,
                         z ? bk : bq, z ? kd : qd, z ? 1.0f : 0.125f,
                         blockIdx.y * 128, blockIdx.x * 64, lds);
  }
}

__global__ __launch_bounds__(256) void oproj_kernel(
    const ushort* __restrict__ Ph, const ushort* __restrict__ Pm,
    const ushort* __restrict__ wsp,
    const float* __restrict__ bias, float* __restrict__ dst) {
  __shared__ ushort lds[2 * 4096 + 2 * 2048];
  const ushort* Bb = wsp + (size_t)3 * 3 * WN;
  gemm_mfma_body<0, 3>(Ph, Pm, nullptr, Bb, Bb + WN, nullptr,
                       bias, dst, 1.0f, blockIdx.y * 128, blockIdx.x * 64, lds);
}

// ---------------- window selection: one wave per (bh, t) ----------------
__global__ __launch_bounds__(256) void window_kernel(
    const float* __restrict__ q, const float* __restrict__ k,
    int* __restrict__ sel) {
  int wid = blockIdx.x * 4 + (threadIdx.x >> 6);
  int lane = threadIdx.x & 63;
  int f = lane & 15, kq = lane >> 4;
  int bh = wid >> 11, t = wid & (TSEQ - 1);
  int start = t - 8;
  if (start < 0) start = 0;
  if (start > TSEQ - 16) start = TSEQ - 16;

  const float* kp = k + ((size_t)bh * TSEQ + start + f) * HD + kq * 8;
  const float* qp = q + ((size_t)bh * TSEQ + t) * HD + kq * 8;
  float kv[16], qv[16];
  *(float4*)&kv[0]  = *(const float4*)(kp + 0);
  *(float4*)&kv[4]  = *(const float4*)(kp + 4);
  *(float4*)&kv[8]  = *(const float4*)(kp + 32);
  *(float4*)&kv[12] = *(const float4*)(kp + 36);
  *(float4*)&qv[0]  = *(const float4*)(qp + 0);
  *(float4*)&qv[4]  = *(const float4*)(qp + 4);
  *(float4*)&qv[8]  = *(const float4*)(qp + 32);
  *(float4*)&qv[12] = *(const float4*)(qp + 36);

  float sp = 0.f, np = 0.f;
#pragma unroll
  for (int i = 0; i < 16; ++i) { sp = fmaf(qv[i], kv[i], sp); np = fmaf(kv[i], kv[i], np); }
  sp += __shfl_xor(sp, 16, 64); sp += __shfl_xor(sp, 32, 64);
  np += __shfl_xor(np, 16, 64); np += __shfl_xor(np, 32, 64);
  float nrm = fmaxf(sqrtf(np), 1e-6f);
  float kn[16];
#pragma unroll
  for (int i = 0; i < 16; ++i) kn[i] = kv[i] / nrm;

  short8 h0, m0, l0, h1, m1, l1;
#pragma unroll
  for (int j = 0; j < 8; ++j) {
    float x = kn[j];
    ushort hb = bf16rne(x); h0[j] = (short)hb;
    float d = x - __uint_as_float((unsigned)hb << 16);
    ushort mb = bf16rne(d); m0[j] = (short)mb;
    l0[j] = (short)bf16rne(d - __uint_as_float((unsigned)mb << 16));
    x = kn[8 + j];
    hb = bf16rne(x); h1[j] = (short)hb;
    d = x - __uint_as_float((unsigned)hb << 16);
    mb = bf16rne(d); m1[j] = (short)mb;
    l1[j] = (short)bf16rne(d - __uint_as_float((unsigned)mb << 16));
  }
  f32x4 g = {0.f, 0.f, 0.f, 0.f};
  g = MFMA_BF16(h0, h0, g); g = MFMA_BF16(h1, h1, g);
  g = MFMA_BF16(m0, h0, g); g = MFMA_BF16(m1, h1, g);
  g = MFMA_BF16(h0, m0, g); g = MFMA_BF16(h1, m1, g);
  g = MFMA_BF16(m0, m0, g); g = MFMA_BF16(m1, m1, g);
  g = MFMA_BF16(l0, h0, g); g = MFMA_BF16(l1, h1, g);
  g = MFMA_BF16(h0, l0, g); g = MFMA_BF16(h1, l1, g);

  int dist = start + f - t; if (dist < 0) dist = -dist;
  float tmp = sp + 0.2f * expf(-(float)dist * 0.125f);

  int* selp = sel + ((size_t)bh * TSEQ + t) * 6;
#pragma unroll
  for (int r = 0; r < 6; ++r) {
    float best = tmp; int bj = f;
    {
      float ov = dppf<0x121>(best); int oi = dppi<0x121>(bj);
      if (ov > best || (ov == best && oi < bj)) { best = ov; bj = oi; }
      ov = dppf<0x122>(best); oi = dppi<0x122>(bj);
      if (ov > best || (ov == best && oi < bj)) { best = ov; bj = oi; }
      ov = dppf<0x124>(best); oi = dppi<0x124>(bj);
      if (ov > best || (ov == best && oi < bj)) { best = ov; bj = oi; }
      ov = dppf<0x128>(best); oi = dppi<0x128>(bj);
      if (ov > best || (ov == best && oi < bj)) { best = ov; bj = oi; }
    }
    if (lane == 0) selp[r] = start + bj;
    if (r < 5) {
      float s01 = (bj & 1) ? g[1] : g[0];
      float s23 = (bj & 1) ? g[3] : g[2];
      float gsel = (bj & 2) ? s23 : s01;
      float grow = __shfl(gsel, ((bj >> 2) << 4) | f, 64);
      tmp -= 0.2f * fmaxf(grow, 0.f);
    }
    if (f == bj) tmp = -1e9f;
  }
}

// ---------------- prototype queries Qp[a][p][:] ----------------
__global__ __launch_bounds__(256) void qp_kernel(const float* __restrict__ q,
                                                 float* __restrict__ Qp) {
  int wid = blockIdx.x * 4 + (threadIdx.x >> 6);
  int lane = threadIdx.x & 63;
  int a = wid >> 5, p = wid & 31;
  int t = c_idxp[p];
  float v = 0.5f * (q[((size_t)(2 * a) * TSEQ + t) * HD + lane] +
                    q[((size_t)(2 * a + 1) * TSEQ + t) * HD + lane]);
  float n2 = wsum(v * v);
  float nrm = fmaxf(sqrtf(n2), 1e-6f);
  Qp[((size_t)a * 32 + p) * HD + lane] = v / nrm;
}

// ---------------- S[a][t][p] and u[a][t] ----------------
__global__ __launch_bounds__(256) void proto_score_kernel(
    const float* __restrict__ k, const float* __restrict__ Qp,
    float* __restrict__ S, float* __restrict__ u) {
  int a = blockIdx.y;
  __shared__ float Qs[2048];
  for (int i = threadIdx.x; i < 2048; i += 256) Qs[i] = Qp[(size_t)a * 2048 + i];
  __syncthreads();
  int w = threadIdx.x >> 6, lane = threadIdx.x & 63;
  int t = blockIdx.x * 4 + w;
  float km = 0.5f * (k[((size_t)(2 * a) * TSEQ + t) * HD + lane] +
                     k[((size_t)(2 * a + 1) * TSEQ + t) * HD + lane]);
  float n2 = wsum(km * km);
  float nrm = fmaxf(sqrtf(n2), 1e-6f);
  float kb = km / nrm;
  float sval = 0.f;
#pragma unroll
  for (int p = 0; p < 32; ++p) {
    float dg = wsum(kb * Qs[p * 64 + lane]);
    dg = fmaxf(dg, 0.f);
    sval = (lane == p) ? dg : sval;
  }
  if (lane < 32) S[((size_t)a * TSEQ + t) * 32 + lane] = sval;
  float x = (lane < 32) ? sval : 0.f;
  float mean = wsum(x) / 32.0f;
  float mx = wmaxr((lane < 32) ? sval : -1e30f);
  float cur = (lane < 32) ? sval : -1e30f;
  float topsum = 0.f;
#pragma unroll
  for (int r = 0; r < 6; ++r) {
    float m = wmaxr(cur);
    topsum += m;
    unsigned long long ball = __ballot(cur == m);
    int first = __ffsll(ball) - 1;
    if (lane == first) cur = -1e30f;
  }
  float dev = (lane < 32) ? (sval - mean) : 0.f;
  float sd = sqrtf(wsum(dev * dev) / 31.0f);
  float uval = ((1.0f * mean + 0.6f * mx) + 0.4f * (topsum / 6.0f)) + 0.2f * sd;
  if (lane == 0) u[(size_t)a * TSEQ + t] = uval;
}

// ---------------- per-head top-12 + greedy facility location ----------------
__global__ void head_select_kernel(const float* __restrict__ u,
                                   const float* __restrict__ S,
                                   int* __restrict__ glob) {
  int a = blockIdx.x;
  int lane = threadIdx.x;
  float uv[32];
#pragma unroll
  for (int c = 0; c < 32; ++c) uv[c] = u[(size_t)a * TSEQ + c * 64 + lane];
  unsigned removed = 0;
  int tidx = 0;
#pragma unroll
  for (int r = 0; r < 12; ++r) {
    float best = -1e30f; int bidx = 1 << 30;
#pragma unroll
    for (int c = 0; c < 32; ++c) {
      if (!((removed >> c) & 1u)) {
        float vv = uv[c]; int gi = c * 64 + lane;
        if (vv > best || (vv == best && gi < bidx)) { best = vv; bidx = gi; }
      }
    }
#pragma unroll
    for (int mS = 1; mS < 64; mS <<= 1) {
      float ov = __shfl_xor(best, mS, 64);
      int oi = __shfl_xor(bidx, mS, 64);
      if (ov > best || (ov == best && oi < bidx)) { best = ov; bidx = oi; }
    }
    if (lane == (bidx & 63)) removed |= 1u << (bidx >> 6);
    if (lane == r) tidx = bidx;
  }
  float srow[12];
#pragma unroll
  for (int r = 0; r < 12; ++r) {
    int tr = __shfl(tidx, r, 64);
    srow[r] = (lane < 32) ? S[((size_t)a * TSEQ + tr) * 32 + lane] : 0.f;
  }
  float m = 0.f;
  unsigned blocked = 0;
#pragma unroll
  for (int g = 0; g < 4; ++g) {
    float gains[12];
#pragma unroll
    for (int r = 0; r < 12; ++r) {
      float gr = (lane < 32) ? fmaxf(srow[r] - m, 0.f) : 0.f;
      gains[r] = wsum(gr);
    }
    float best = -1e30f; int bj = 0;
#pragma unroll
    for (int r = 0; r < 12; ++r) {
      float vv = ((blocked >> r) & 1u) ? -1e9f : gains[r];
      if (vv > best) { best = vv; bj = r; }
    }
    blocked |= 1u << bj;
#pragma unroll
    for (int r = 0; r < 12; ++r) m = (r == bj) ? fmaxf(m, srow[r]) : m;
    int gidx = __shfl(tidx, bj, 64);
    if (lane == 0) glob[a * 4 + g] = gidx;
  }
}

// -------- final 10-candidate attention; emits (h,m) bf16 split directly -----
__global__ __launch_bounds__(256) void attend_kernel(
    const float* __restrict__ q, const float* __restrict__ k,
    const float* __restrict__ v, const int* __restrict__ sel,
    const int* __restrict__ glob, ushort* __restrict__ Ph,
    ushort* __restrict__ Pm) {
  int wid = blockIdx.x * 4 + (threadIdx.x >> 6);
  int lane = threadIdx.x & 63;
  int bh = wid >> 11, t = wid & (TSEQ - 1);
  int h = bh % NH, b = bh / NH;
  float qv = q[((size_t)bh * TSEQ + t) * HD + lane];
  int cand[10];
  const int* selp = sel + ((size_t)bh * TSEQ + t) * 6;
#pragma unroll
  for (int c = 0; c < 6; ++c) cand[c] = selp[c];
#pragma unroll
  for (int c = 0; c < 4; ++c) cand[6 + c] = glob[h * 4 + c];
  float sc[10];
#pragma unroll
  for (int c = 0; c < 10; ++c) {
    float kv = k[((size_t)bh * TSEQ + cand[c]) * HD + lane];
    sc[c] = wsum(qv * kv);
  }
  float mx = sc[0];
#pragma unroll
  for (int c = 1; c < 10; ++c) mx = fmaxf(mx, sc[c]);
  float e[10], den = 0.f;
#pragma unroll
  for (int c = 0; c < 10; ++c) { e[c] = expf(sc[c] - mx); den += e[c]; }
  float o = 0.f;
#pragma unroll
  for (int c = 0; c < 10; ++c) {
    float w = e[c] / den;
    o += w * v[((size_t)bh * TSEQ + cand[c]) * HD + lane];
  }
  size_t idx = ((size_t)b * TSEQ + t) * DM + h * HD + lane;
  ushort hb = bf16rne(o);
  float d = o - __uint_as_float((unsigned)hb << 16);
  Ph[idx] = hb;
  Pm[idx] = bf16rne(d);
}

extern "C" void kernel_launch(void* const* d_in, const int* in_sizes, int n_in,
                              void* d_out, int out_size, void* d_ws, size_t ws_size,
                              hipStream_t stream) {
  const float* x  = (const float*)d_in[0];
  const float* Wq = (const float*)d_in[1];
  const float* bq = (const float*)d_in[2];
  const float* Wk = (const float*)d_in[3];
  const float* bk = (const float*)d_in[4];
  const float* Wv = (const float*)d_in[5];
  const float* bv = (const float*)d_in[6];
  const float* Wo = (const float*)d_in[7];
  const float* bo = (const float*)d_in[8];
  float* out = (float*)d_out;

  float* ws = (float*)d_ws;
  const size_t QKV = (size_t)NBH * TSEQ * HD;  // 3145728
  float* qb = ws;
  float* kb = qb + QKV;
  float* vb = kb + QKV;
  float* slotA = vb + QKV;                     // QKV floats: Xh+Xm, later Ph+Pm
  float* Qp = slotA + QKV;
  float* S  = Qp + (size_t)NH * 32 * HD;
  float* u  = S + (size_t)NH * TSEQ * 32;
  int* sel  = (int*)(u + (size_t)NH * TSEQ);
  int* glob = sel + (size_t)NBH * TSEQ * 6;
  ushort* wsp = (ushort*)(glob + 64);          // 12 x WN ushorts = 14.16 MB
  ushort* Xl  = wsp + (size_t)12 * WN;         // QKV ushorts = 6.29 MB

  ushort* Xh = (ushort*)slotA;
  ushort* Xm = Xh + QKV;
  ushort* Ph = Xh;  // reused after last X read (qkv) — attend runs later
  ushort* Pm = Xm;

  convert_kernel<<<dim3(1536, 5), 256, 0, stream>>>(
      x, Wq, Wk, Wv, Wo, Xh, Xm, Xl, wsp);
  qkv_kernel<<<dim3(12, 32, 3), 256, 0, stream>>>(
      Xh, Xm, Xl, wsp, bq, qb, bk, kb, bv, vb);
  window_kernel<<<12288, 256, 0, stream>>>(qb, kb, sel);
  qp_kernel<<<96, 256, 0, stream>>>(qb, Qp);
  proto_score_kernel<<<dim3(512, NH), 256, 0, stream>>>(kb, Qp, S, u);
  head_select_kernel<<<NH, 64, 0, stream>>>(u, S, glob);
  attend_kernel<<<12288, 256, 0, stream>>>(qb, kb, vb, sel, glob, Ph, Pm);
  oproj_kernel<<<dim3(12, 32), 256, 0, stream>>>(Ph, Pm, wsp, bo, out);
}